// Round 4
// baseline (759.071 us; speedup 1.0000x reference)
//
#include <hip/hip_runtime.h>
#include <hip/hip_bf16.h>

constexpr int NN = 50000;
constexpr int NE = 800000;

// ---------- degree / dinv ----------
__global__ __launch_bounds__(256) void deg_kernel(const int* __restrict__ dst,
                                                  float* __restrict__ deg, int E) {
    int e = blockIdx.x * 256 + threadIdx.x;
    if (e < E) atomicAdd(&deg[dst[e]], 1.0f);
}

__global__ __launch_bounds__(256) void dinv_kernel(float* deg, int M) {
    int i = blockIdx.x * 256 + threadIdx.x;
    if (i < M) deg[i] = rsqrtf(deg[i] + 1.0f);  // +1 = self loop
}

// ---------- GEMM: H[M x N] (compact) = X[M x K] @ W[:, wc0:wc0+N] ----------
// X fp32 [M x K] row-major (row stride = K); W fp32 [K x WN] row-major.
template <int K, int N, int WN>
__global__ __launch_bounds__(256) void gemm_kernel(const float* __restrict__ X,
                                                   const float* __restrict__ W,
                                                   int wc0,
                                                   float* __restrict__ H, int M) {
    constexpr int ROWS = 64;

    __shared__ float Xs[ROWS * K];
    __shared__ float Ws[K * N];

    const int tid = threadIdx.x;
    const int rb  = blockIdx.x * ROWS;

    // stage W chunk, 16B vectors (4 floats per uint4)
    {
        const uint4* Wv  = reinterpret_cast<const uint4*>(W);
        uint4*       Wsv = reinterpret_cast<uint4*>(Ws);
        constexpr int VPW = N / 4;    // uint4 per chunk row
        constexpr int VWR = WN / 4;   // uint4 per full W row
        const int cv0 = wc0 / 4;
        for (int i = tid; i < K * VPW; i += 256) {
            int k = i / VPW, jv = i - k * VPW;
            Wsv[i] = Wv[k * VWR + cv0 + jv];
        }
    }
    // stage X rows [rb, rb+ROWS), 16B vectors, zero-fill OOB rows
    {
        const uint4* Xv  = reinterpret_cast<const uint4*>(X + (size_t)rb * K);
        uint4*       Xsv = reinterpret_cast<uint4*>(Xs);
        constexpr int VPR = K / 4;  // uint4 per row
        for (int i = tid; i < ROWS * VPR; i += 256) {
            int r = i / VPR;
            uint4 v = make_uint4(0u, 0u, 0u, 0u);
            if (rb + r < M) v = Xv[i];
            Xsv[i] = v;
        }
    }
    __syncthreads();

    constexpr int CP  = N / 2;        // col-pairs
    constexpr int NRG = 256 / CP;     // row groups
    constexpr int RPT = ROWS / NRG;   // rows per thread

    const int cp = tid % CP;
    const int rg = tid / CP;

    float acc[RPT][2];
#pragma unroll
    for (int i = 0; i < RPT; i++) { acc[i][0] = 0.f; acc[i][1] = 0.f; }

    const float2* Wp2 = reinterpret_cast<const float2*>(Ws);

#pragma unroll 4
    for (int k = 0; k < K; k++) {
        float2 wp = Wp2[(k * N) / 2 + cp];
#pragma unroll
        for (int i = 0; i < RPT; i++) {
            float xv = Xs[(rg * RPT + i) * K + k];
            acc[i][0] += xv * wp.x;
            acc[i][1] += xv * wp.y;
        }
    }

    const int c0 = 2 * cp;
#pragma unroll
    for (int i = 0; i < RPT; i++) {
        int row = rb + rg * RPT + i;
        if (row < M) {
            float2* o = reinterpret_cast<float2*>(H + (size_t)row * N + c0);
            *o = make_float2(acc[i][0], acc[i][1]);
        }
    }
}

// ---------- edge scatter: one thread per (edge, col) ----------
// agg[dst*N + d] += h[src*N + d] * dinv[src]*dinv[dst]
template <int N>
__global__ __launch_bounds__(256) void scatter_kernel(const int* __restrict__ src,
                                                      const int* __restrict__ dst,
                                                      const float* __restrict__ dinv,
                                                      const float* __restrict__ h,
                                                      float* __restrict__ agg, int E) {
    int gid = blockIdx.x * 256 + threadIdx.x;
    int e = gid / N;
    int d = gid - e * N;
    if (e >= E) return;
    int s = src[e];
    int t = dst[e];
    float norm = dinv[s] * dinv[t];
    atomicAdd(&agg[(size_t)t * N + d], h[(size_t)s * N + d] * norm);
}

// ---------- finalize: v = agg + ht*dinv^2 + b[bc0+col]; opt relu; fp32 out ----------
template <int N, bool RELU>
__global__ __launch_bounds__(256) void finalize_kernel(const float* __restrict__ ht,   // [M x N]
                                                       const float* __restrict__ agg,  // [M x N]
                                                       const float* __restrict__ dinv,
                                                       const float* __restrict__ b, int bc0,
                                                       float* __restrict__ out,
                                                       int ostride, int oc0, int M) {
    int idx = blockIdx.x * 256 + threadIdx.x;
    if (idx >= M * N) return;
    int row = idx / N;
    int col = idx - row * N;
    float di = dinv[row];
    float v = agg[idx] + ht[idx] * di * di + b[bc0 + col];
    if (RELU) v = fmaxf(v, 0.f);
    out[(size_t)row * ostride + oc0 + col] = v;
}

// ---------- templated driver over chunk width ----------
template <int WC>
static void run_pipeline(const float* x, const int* src, const int* dst,
                         const float* W1, const float* b1,
                         const float* W2, const float* b2,
                         float* out_h2, float* out_h1,
                         float* deg, float* T, float* agg, hipStream_t stream) {
    // degrees -> dinv
    hipMemsetAsync(deg, 0, 50048 * sizeof(float), stream);
    deg_kernel<<<(NE + 255) / 256, 256, 0, stream>>>(dst, deg, NE);
    dinv_kernel<<<(NN + 255) / 256, 256, 0, stream>>>(deg, NN);

    const int gB = (NN + 63) / 64;                 // gemm blocks
    const int sB = (int)(((size_t)NE * WC + 255) / 256);   // scatter blocks
    const int fB = (NN * WC + 255) / 256;          // finalize blocks

    // ----- layer 1: h1 = relu(norm-agg(x@W1) + b1) -> fp32 out_h1 -----
    for (int c0 = 0; c0 < 128; c0 += WC) {
        gemm_kernel<128, WC, 128><<<gB, 256, 0, stream>>>(x, W1, c0, T, NN);
        hipMemsetAsync(agg, 0, (size_t)NN * WC * sizeof(float), stream);
        scatter_kernel<WC><<<sB, 256, 0, stream>>>(src, dst, deg, T, agg, NE);
        finalize_kernel<WC, true><<<fB, 256, 0, stream>>>(T, agg, deg, b1, c0,
                                                          out_h1, 128, c0, NN);
    }
    // ----- layer 2: h2 = norm-agg(h1@W2) + b2, input = fp32 h1 in out_h1 -----
    for (int c0 = 0; c0 < 64; c0 += WC) {
        gemm_kernel<128, WC, 64><<<gB, 256, 0, stream>>>(out_h1, W2, c0, T, NN);
        hipMemsetAsync(agg, 0, (size_t)NN * WC * sizeof(float), stream);
        scatter_kernel<WC><<<sB, 256, 0, stream>>>(src, dst, deg, T, agg, NE);
        finalize_kernel<WC, false><<<fB, 256, 0, stream>>>(T, agg, deg, b2, c0,
                                                           out_h2, 64, c0, NN);
    }
}

extern "C" void kernel_launch(void* const* d_in, const int* in_sizes, int n_in,
                              void* d_out, int out_size, void* d_ws, size_t ws_size,
                              hipStream_t stream) {
    const float* x  = (const float*)d_in[0];
    const int*   ei = (const int*)d_in[1];
    const float* W1 = (const float*)d_in[2];
    const float* b1 = (const float*)d_in[3];
    const float* W2 = (const float*)d_in[4];
    const float* b2 = (const float*)d_in[5];

    float* out_h2 = (float*)d_out;                 // [NN x 64]  (output 0)
    float* out_h1 = out_h2 + (size_t)NN * 64;      // [NN x 128] (output 1)

    const int* src = ei;        // edge_index[0]
    const int* dst = ei + NE;   // edge_index[1]

    // ws layout (fp32): [deg/dinv : 50048][T : NN*WC][agg : NN*WC]
    float* ws = (float*)d_ws;
    auto need = [](int w) -> size_t {
        return (size_t)(50048 + 2 * (size_t)NN * w) * sizeof(float);
    };
    // chunk width chosen from ws_size (constant per session -> graph-safe)
    int WC = (need(64) <= ws_size) ? 64
           : (need(32) <= ws_size) ? 32
           : (need(16) <= ws_size) ? 16 : 8;

    float* deg = ws;
    float* T   = ws + 50048;
    float* agg = T + (size_t)NN * WC;

    switch (WC) {
        case 64: run_pipeline<64>(x, src, dst, W1, b1, W2, b2, out_h2, out_h1, deg, T, agg, stream); break;
        case 32: run_pipeline<32>(x, src, dst, W1, b1, W2, b2, out_h2, out_h1, deg, T, agg, stream); break;
        case 16: run_pipeline<16>(x, src, dst, W1, b1, W2, b2, out_h2, out_h1, deg, T, agg, stream); break;
        default: run_pipeline<8>(x, src, dst, W1, b1, W2, b2, out_h2, out_h1, deg, T, agg, stream); break;
    }
}

// Round 5
// 472.219 us; speedup vs baseline: 1.6075x; 1.6075x over previous
//
#include <hip/hip_runtime.h>
#include <hip/hip_bf16.h>

constexpr int NN = 50000;
constexpr int NE = 800000;

// ---------- degree (int) ----------
__global__ __launch_bounds__(256) void deg_kernel(const int* __restrict__ dst,
                                                  int* __restrict__ deg, int E) {
    int e = blockIdx.x * 256 + threadIdx.x;
    if (e < E) atomicAdd(&deg[dst[e]], 1);
}

__global__ __launch_bounds__(256) void dinv_kernel(const int* __restrict__ deg,
                                                   float* __restrict__ dinv, int M) {
    int i = blockIdx.x * 256 + threadIdx.x;
    if (i < M) dinv[i] = rsqrtf((float)deg[i] + 1.0f);  // +1 = self loop
}

// ---------- single-block exclusive scan: rowptr & cursor from deg ----------
__global__ __launch_bounds__(256) void scan_kernel(const int* __restrict__ deg,
                                                   int* __restrict__ rowptr,
                                                   int* __restrict__ cursor, int n) {
    __shared__ int wsum[4];
    __shared__ int woff[4];
    __shared__ int carry_s;
    const int tid  = threadIdx.x;
    const int lane = tid & 63;
    const int wid  = tid >> 6;
    if (tid == 0) carry_s = 0;
    __syncthreads();
    for (int base = 0; base < n; base += 1024) {
        int idx = base + tid * 4;
        int v0 = (idx + 0 < n) ? deg[idx + 0] : 0;
        int v1 = (idx + 1 < n) ? deg[idx + 1] : 0;
        int v2 = (idx + 2 < n) ? deg[idx + 2] : 0;
        int v3 = (idx + 3 < n) ? deg[idx + 3] : 0;
        int local = v0 + v1 + v2 + v3;
        int incl = local;
        for (int off = 1; off < 64; off <<= 1) {
            int t = __shfl_up(incl, off, 64);
            if (lane >= off) incl += t;
        }
        if (lane == 63) wsum[wid] = incl;
        __syncthreads();
        if (tid == 0) {
            int acc = carry_s;
            for (int w = 0; w < 4; w++) { woff[w] = acc; acc += wsum[w]; }
            carry_s = acc;
        }
        __syncthreads();
        int p = woff[wid] + (incl - local);
        if (idx + 0 < n) { rowptr[idx + 0] = p; cursor[idx + 0] = p; } p += v0;
        if (idx + 1 < n) { rowptr[idx + 1] = p; cursor[idx + 1] = p; } p += v1;
        if (idx + 2 < n) { rowptr[idx + 2] = p; cursor[idx + 2] = p; } p += v2;
        if (idx + 3 < n) { rowptr[idx + 3] = p; cursor[idx + 3] = p; }
        // no trailing sync needed: wsum is only read inside the tid0 window above
    }
    if (tid == 0) rowptr[n] = carry_s;
}

// ---------- CSR fill: bucket edges by dst, fold dinv[src] per edge ----------
__global__ __launch_bounds__(256) void fill_kernel(const int* __restrict__ src,
                                                   const int* __restrict__ dst,
                                                   const float* __restrict__ dinv,
                                                   int* __restrict__ cursor,
                                                   int* __restrict__ srcs,
                                                   float* __restrict__ wsrc, int E) {
    int e = blockIdx.x * 256 + threadIdx.x;
    if (e >= E) return;
    int s = src[e], t = dst[e];
    int pos = atomicAdd(&cursor[t], 1);
    srcs[pos] = s;
    wsrc[pos] = dinv[s];
}

// ---------- GEMM: H[M x N] (compact) = X[M x K] @ W[:, wc0:wc0+N], fp32 ----------
template <int K, int N, int WN>
__global__ __launch_bounds__(256) void gemm_kernel(const float* __restrict__ X,
                                                   const float* __restrict__ W,
                                                   int wc0,
                                                   float* __restrict__ H, int M) {
    constexpr int ROWS = 64;

    __shared__ float Xs[ROWS * K];
    __shared__ float Ws[K * N];

    const int tid = threadIdx.x;
    const int rb  = blockIdx.x * ROWS;

    {
        const uint4* Wv  = reinterpret_cast<const uint4*>(W);
        uint4*       Wsv = reinterpret_cast<uint4*>(Ws);
        constexpr int VPW = N / 4;
        constexpr int VWR = WN / 4;
        const int cv0 = wc0 / 4;
        for (int i = tid; i < K * VPW; i += 256) {
            int k = i / VPW, jv = i - k * VPW;
            Wsv[i] = Wv[k * VWR + cv0 + jv];
        }
    }
    {
        const uint4* Xv  = reinterpret_cast<const uint4*>(X + (size_t)rb * K);
        uint4*       Xsv = reinterpret_cast<uint4*>(Xs);
        constexpr int VPR = K / 4;
        for (int i = tid; i < ROWS * VPR; i += 256) {
            int r = i / VPR;
            uint4 v = make_uint4(0u, 0u, 0u, 0u);
            if (rb + r < M) v = Xv[i];
            Xsv[i] = v;
        }
    }
    __syncthreads();

    constexpr int CP  = N / 2;
    constexpr int NRG = 256 / CP;
    constexpr int RPT = ROWS / NRG;

    const int cp = tid % CP;
    const int rg = tid / CP;

    float acc[RPT][2];
#pragma unroll
    for (int i = 0; i < RPT; i++) { acc[i][0] = 0.f; acc[i][1] = 0.f; }

    const float2* Wp2 = reinterpret_cast<const float2*>(Ws);

#pragma unroll 4
    for (int k = 0; k < K; k++) {
        float2 wp = Wp2[(k * N) / 2 + cp];
#pragma unroll
        for (int i = 0; i < RPT; i++) {
            float xv = Xs[(rg * RPT + i) * K + k];
            acc[i][0] += xv * wp.x;
            acc[i][1] += xv * wp.y;
        }
    }

    const int c0 = 2 * cp;
#pragma unroll
    for (int i = 0; i < RPT; i++) {
        int row = rb + rg * RPT + i;
        if (row < M) {
            float2* o = reinterpret_cast<float2*>(H + (size_t)row * N + c0);
            *o = make_float2(acc[i][0], acc[i][1]);
        }
    }
}

// ---------- fused gather-aggregate + self-loop + bias (+relu): wave per node ----------
// out[t, oc0+lane] = relu( dinv[t] * sum_e dinv[src_e]*h[src_e,lane]
//                          + h[t,lane]*dinv[t]^2 + b[bc0+lane] )
template <int N, bool RELU>
__global__ __launch_bounds__(256) void gather_kernel(const int* __restrict__ rowptr,
                                                     const int* __restrict__ srcs,
                                                     const float* __restrict__ wsrc,
                                                     const float* __restrict__ dinv,
                                                     const float* __restrict__ h,   // [M x N]
                                                     const float* __restrict__ b, int bc0,
                                                     float* __restrict__ out,
                                                     int ostride, int oc0, int M) {
    const int lane = threadIdx.x & 63;
    const int wid  = threadIdx.x >> 6;
    const int t    = blockIdx.x * 4 + wid;
    if (t >= M) return;

    float acc = 0.f;
    const int beg = rowptr[t], end = rowptr[t + 1];
    for (int eb = beg; eb < end; eb += 64) {
        const int rem = end - eb;
        int   sv = 0;
        float wv = 0.f;
        if (lane < rem) { sv = srcs[eb + lane]; wv = wsrc[eb + lane]; }
        const int m = rem < 64 ? rem : 64;
        for (int j = 0; j < m; j++) {
            int   s = __shfl(sv, j);
            float w = __shfl(wv, j);
            acc += w * h[(size_t)s * N + lane];
        }
    }
    const float di = dinv[t];
    float v = acc * di + h[(size_t)t * N + lane] * di * di + b[bc0 + lane];
    if (RELU) v = fmaxf(v, 0.f);
    out[(size_t)t * ostride + oc0 + lane] = v;
}

extern "C" void kernel_launch(void* const* d_in, const int* in_sizes, int n_in,
                              void* d_out, int out_size, void* d_ws, size_t ws_size,
                              hipStream_t stream) {
    const float* x  = (const float*)d_in[0];
    const int*   ei = (const int*)d_in[1];
    const float* W1 = (const float*)d_in[2];
    const float* b1 = (const float*)d_in[3];
    const float* W2 = (const float*)d_in[4];
    const float* b2 = (const float*)d_in[5];

    float* out_h2 = (float*)d_out;                 // [NN x 64]  (output 0)
    float* out_h1 = out_h2 + (size_t)NN * 64;      // [NN x 128] (output 1)

    const int* src = ei;        // edge_index[0]
    const int* dst = ei + NE;   // edge_index[1]

    // ws layout (4B words), total 20.0 MB (< proven 25.8 MB):
    //   deg_i   [50048] | rowptr [50064] | cursor [50048] | dinv [50048]
    //   srcs    [800000] | wsrc  [800000] | T [NN*64]
    int*   wsw    = (int*)d_ws;
    int*   deg_i  = wsw;
    int*   rowptr = wsw + 50048;
    int*   cursor = wsw + 100112;
    float* dinv   = (float*)(wsw + 150160);
    int*   srcs   = wsw + 200208;
    float* wsrc   = (float*)(wsw + 1000208);
    float* T      = (float*)(wsw + 1800208);

    // ----- CSR build (once per launch; ws is re-poisoned every call) -----
    hipMemsetAsync(deg_i, 0, 50048 * sizeof(int), stream);
    deg_kernel<<<(NE + 255) / 256, 256, 0, stream>>>(dst, deg_i, NE);
    scan_kernel<<<1, 256, 0, stream>>>(deg_i, rowptr, cursor, NN);
    dinv_kernel<<<(NN + 255) / 256, 256, 0, stream>>>(deg_i, dinv, NN);
    fill_kernel<<<(NE + 255) / 256, 256, 0, stream>>>(src, dst, dinv, cursor, srcs, wsrc, NE);

    const int gB = (NN + 63) / 64;   // gemm blocks
    const int aB = (NN + 3) / 4;     // gather blocks (wave per node)

    // ----- layer 1: two 64-col chunks; h1 -> fp32 out_h1 (fed un-rounded to L2) -----
    for (int c0 = 0; c0 < 128; c0 += 64) {
        gemm_kernel<128, 64, 128><<<gB, 256, 0, stream>>>(x, W1, c0, T, NN);
        gather_kernel<64, true><<<aB, 256, 0, stream>>>(rowptr, srcs, wsrc, dinv, T,
                                                        b1, c0, out_h1, 128, c0, NN);
    }
    // ----- layer 2 -----
    gemm_kernel<128, 64, 64><<<gB, 256, 0, stream>>>(out_h1, W2, 0, T, NN);
    gather_kernel<64, false><<<aB, 256, 0, stream>>>(rowptr, srcs, wsrc, dinv, T,
                                                     b2, 0, out_h2, 64, 0, NN);
}

// Round 6
// 376.344 us; speedup vs baseline: 2.0170x; 1.2548x over previous
//
#include <hip/hip_runtime.h>
#include <hip/hip_bf16.h>

constexpr int NN = 50000;
constexpr int NE = 800000;
constexpr int SCAN_B = 1024;                      // elems per scan block
constexpr int NB = (NN + SCAN_B - 1) / SCAN_B;    // 49 scan blocks

// ---------- degree (int) ----------
__global__ __launch_bounds__(256) void deg_kernel(const int* __restrict__ dst,
                                                  int* __restrict__ deg, int E) {
    int e = blockIdx.x * 256 + threadIdx.x;
    if (e < E) atomicAdd(&deg[dst[e]], 1);
}

__global__ __launch_bounds__(256) void dinv_kernel(const int* __restrict__ deg,
                                                   float* __restrict__ dinv, int M) {
    int i = blockIdx.x * 256 + threadIdx.x;
    if (i < M) dinv[i] = rsqrtf((float)deg[i] + 1.0f);  // +1 = self loop
}

// ---------- parallel scan, phase 1: per-block sums ----------
__global__ __launch_bounds__(256) void scan_part(const int* __restrict__ deg,
                                                 int* __restrict__ bsum, int n) {
    __shared__ int wred[4];
    const int tid = threadIdx.x, lane = tid & 63, wid = tid >> 6;
    int idx = blockIdx.x * SCAN_B + tid * 4;
    int s = 0;
#pragma unroll
    for (int j = 0; j < 4; j++) if (idx + j < n) s += deg[idx + j];
#pragma unroll
    for (int off = 32; off >= 1; off >>= 1) s += __shfl_xor(s, off);
    if (lane == 0) wred[wid] = s;
    __syncthreads();
    if (tid == 0) bsum[blockIdx.x] = wred[0] + wred[1] + wred[2] + wred[3];
}

// ---------- phase 2: one-wave exclusive scan of block sums ----------
__global__ __launch_bounds__(64) void scan_tops(const int* __restrict__ bsum,
                                                int* __restrict__ boff,
                                                int* __restrict__ total_out, int nb) {
    int lane = threadIdx.x;
    int v = (lane < nb) ? bsum[lane] : 0;
    int incl = v;
#pragma unroll
    for (int off = 1; off < 64; off <<= 1) {
        int t = __shfl_up(incl, off, 64);
        if (lane >= off) incl += t;
    }
    if (lane < nb) boff[lane] = incl - v;
    if (lane == 63) total_out[0] = incl;   // = rowptr[n]
}

// ---------- phase 3: per-block scan + global offset -> rowptr & cursor ----------
__global__ __launch_bounds__(256) void scan_fill(const int* __restrict__ deg,
                                                 const int* __restrict__ boff,
                                                 int* __restrict__ rowptr,
                                                 int* __restrict__ cursor, int n) {
    __shared__ int wsum[4];
    __shared__ int woff[4];
    const int tid = threadIdx.x, lane = tid & 63, wid = tid >> 6;
    int idx = blockIdx.x * SCAN_B + tid * 4;
    int v0 = (idx + 0 < n) ? deg[idx + 0] : 0;
    int v1 = (idx + 1 < n) ? deg[idx + 1] : 0;
    int v2 = (idx + 2 < n) ? deg[idx + 2] : 0;
    int v3 = (idx + 3 < n) ? deg[idx + 3] : 0;
    int local = v0 + v1 + v2 + v3;
    int incl = local;
#pragma unroll
    for (int off = 1; off < 64; off <<= 1) {
        int t = __shfl_up(incl, off, 64);
        if (lane >= off) incl += t;
    }
    if (lane == 63) wsum[wid] = incl;
    __syncthreads();
    if (tid == 0) {
        int acc = boff[blockIdx.x];
        for (int w = 0; w < 4; w++) { woff[w] = acc; acc += wsum[w]; }
    }
    __syncthreads();
    int p = woff[wid] + (incl - local);
    if (idx + 0 < n) { rowptr[idx + 0] = p; cursor[idx + 0] = p; } p += v0;
    if (idx + 1 < n) { rowptr[idx + 1] = p; cursor[idx + 1] = p; } p += v1;
    if (idx + 2 < n) { rowptr[idx + 2] = p; cursor[idx + 2] = p; } p += v2;
    if (idx + 3 < n) { rowptr[idx + 3] = p; cursor[idx + 3] = p; }
}

// ---------- CSR fill: bucket edges by dst, fold dinv[src] per edge ----------
__global__ __launch_bounds__(256) void fill_kernel(const int* __restrict__ src,
                                                   const int* __restrict__ dst,
                                                   const float* __restrict__ dinv,
                                                   int* __restrict__ cursor,
                                                   int* __restrict__ srcs,
                                                   float* __restrict__ wsrc, int E) {
    int e = blockIdx.x * 256 + threadIdx.x;
    if (e >= E) return;
    int s = src[e], t = dst[e];
    int pos = atomicAdd(&cursor[t], 1);
    srcs[pos] = s;
    wsrc[pos] = dinv[s];
}

// ---------- GEMM: H[:, oc0:oc0+N] = X[M x K] @ W[:, wc0:wc0+N]  (fp32) ----------
// 4x4 register blocking, b128 LDS reads, K-tiled W staging (48 KB LDS, 3 blk/CU).
template <int K, int N, int WN, int OS>
__global__ __launch_bounds__(256) void gemm_kernel(const float* __restrict__ X,
                                                   const float* __restrict__ W,
                                                   int wc0, int oc0,
                                                   float* __restrict__ H, int M) {
    constexpr int ROWS = 64;
    constexpr int KT   = 64;          // K-tile for W staging
    constexpr int XS   = K + 4;       // padded X row stride (floats): rg-groups 2-way, not 4-way
    constexpr int CP   = N / 4;       // col groups (float4 each)
    constexpr int NRG  = 256 / CP;
    constexpr int RPT  = ROWS / NRG;  // rows per thread (=4)

    __shared__ float Xs[ROWS * XS];
    __shared__ float Ws[KT * N];

    const int tid = threadIdx.x;
    const int rb  = blockIdx.x * ROWS;
    const int cp  = tid % CP;
    const int rg  = tid / CP;
    const int r0  = rg * RPT;

    // stage X rows [rb, rb+ROWS) into padded LDS, float4, zero-fill OOB
    {
        const float4* Xv  = reinterpret_cast<const float4*>(X + (size_t)rb * K);
        float4*       Xsv = reinterpret_cast<float4*>(Xs);
        constexpr int VPR = K / 4;  // float4 per row
        for (int i = tid; i < ROWS * VPR; i += 256) {
            int r = i / VPR, j = i - r * VPR;
            float4 v = make_float4(0.f, 0.f, 0.f, 0.f);
            if (rb + r < M) v = Xv[i];
            Xsv[r * (XS / 4) + j] = v;
        }
    }

    float4 acc[RPT];
#pragma unroll
    for (int i = 0; i < RPT; i++) acc[i] = make_float4(0.f, 0.f, 0.f, 0.f);

    for (int kt = 0; kt < K; kt += KT) {
        // stage W tile [kt, kt+KT) x [wc0, wc0+N)
        {
            const float4* Wv  = reinterpret_cast<const float4*>(W);
            float4*       Wsv = reinterpret_cast<float4*>(Ws);
            constexpr int VPW = N / 4;
            constexpr int VWR = WN / 4;
            const int cv0 = wc0 / 4;
            for (int i = tid; i < KT * VPW; i += 256) {
                int k = i / VPW, j = i - k * VPW;
                Wsv[i] = Wv[(kt + k) * VWR + cv0 + j];
            }
        }
        __syncthreads();

        const float4* Xs4 = reinterpret_cast<const float4*>(Xs);
        const float4* Ws4 = reinterpret_cast<const float4*>(Ws);
#pragma unroll 4
        for (int k4 = 0; k4 < KT; k4 += 4) {
            float4 xq[RPT];
#pragma unroll
            for (int i = 0; i < RPT; i++)
                xq[i] = Xs4[(r0 + i) * (XS / 4) + (kt + k4) / 4];
            float4 wq[4];
#pragma unroll
            for (int j = 0; j < 4; j++)
                wq[j] = Ws4[(k4 + j) * CP + cp];
#pragma unroll
            for (int j = 0; j < 4; j++) {
#pragma unroll
                for (int i = 0; i < RPT; i++) {
                    float xx = reinterpret_cast<const float*>(&xq[i])[j];
                    acc[i].x += xx * wq[j].x;
                    acc[i].y += xx * wq[j].y;
                    acc[i].z += xx * wq[j].z;
                    acc[i].w += xx * wq[j].w;
                }
            }
        }
        __syncthreads();
    }

#pragma unroll
    for (int i = 0; i < RPT; i++) {
        int row = rb + r0 + i;
        if (row < M) {
            float4* o = reinterpret_cast<float4*>(H + (size_t)row * OS + oc0 + 4 * cp);
            *o = acc[i];
        }
    }
}

// ---------- fused gather-aggregate + self-loop + bias (+relu): wave per node ----------
// out[t, :] = [relu]( dinv[t] * sum_e dinv[src_e]*h[src_e,:] + h[t,:]*dinv[t]^2 + b )
template <int NW, bool RELU>
__global__ __launch_bounds__(256) void gather_kernel(const int* __restrict__ rowptr,
                                                     const int* __restrict__ srcs,
                                                     const float* __restrict__ wsrc,
                                                     const float* __restrict__ dinv,
                                                     const float* __restrict__ h,   // [M x NW]
                                                     const float* __restrict__ b,
                                                     float* __restrict__ out, int M) {
    constexpr int VEC = NW / 64;   // floats per lane (1 or 2)
    const int lane = threadIdx.x & 63;
    const int wid  = threadIdx.x >> 6;
    const int t    = blockIdx.x * 4 + wid;
    if (t >= M) return;

    float acc0 = 0.f, acc1 = 0.f;
    const int beg = rowptr[t], end = rowptr[t + 1];
    for (int eb = beg; eb < end; eb += 64) {
        const int rem = end - eb;
        int   sv = 0;
        float wv = 0.f;
        if (lane < rem) { sv = srcs[eb + lane]; wv = wsrc[eb + lane]; }
        const int m = rem < 64 ? rem : 64;
        for (int j = 0; j < m; j++) {
            int   s = __shfl(sv, j);
            float w = __shfl(wv, j);
            const float* hr = h + (size_t)s * NW + lane * VEC;
            if constexpr (VEC == 2) {
                float2 hv = *reinterpret_cast<const float2*>(hr);
                acc0 += w * hv.x;
                acc1 += w * hv.y;
            } else {
                acc0 += w * hr[0];
            }
        }
    }
    const float di = dinv[t];
    const float* hs = h + (size_t)t * NW + lane * VEC;
    float* op = out + (size_t)t * NW + lane * VEC;
    if constexpr (VEC == 2) {
        float2 sv = *reinterpret_cast<const float2*>(hs);
        float2 bv = *reinterpret_cast<const float2*>(b + lane * 2);
        float v0 = acc0 * di + sv.x * di * di + bv.x;
        float v1 = acc1 * di + sv.y * di * di + bv.y;
        if (RELU) { v0 = fmaxf(v0, 0.f); v1 = fmaxf(v1, 0.f); }
        *reinterpret_cast<float2*>(op) = make_float2(v0, v1);
    } else {
        float v0 = acc0 * di + hs[0] * di * di + b[lane];
        if (RELU) v0 = fmaxf(v0, 0.f);
        op[0] = v0;
    }
}

extern "C" void kernel_launch(void* const* d_in, const int* in_sizes, int n_in,
                              void* d_out, int out_size, void* d_ws, size_t ws_size,
                              hipStream_t stream) {
    const float* x  = (const float*)d_in[0];
    const int*   ei = (const int*)d_in[1];
    const float* W1 = (const float*)d_in[2];
    const float* b1 = (const float*)d_in[3];
    const float* W2 = (const float*)d_in[4];
    const float* b2 = (const float*)d_in[5];

    float* out_h2 = (float*)d_out;                 // [NN x 64]  (output 0)
    float* out_h1 = out_h2 + (size_t)NN * 64;      // [NN x 128] (output 1)

    const int* src = ei;        // edge_index[0]
    const int* dst = ei + NE;   // edge_index[1]

    // ws layout (4B words), total 32.8 MB (ws_size >= 38.6 MB proven by r1/r2 memsets):
    int*   wsw    = (int*)d_ws;
    int*   deg_i  = wsw;                      //  50048
    int*   rowptr = wsw + 50048;              //  50064
    int*   cursor = wsw + 100112;             //  50048
    float* dinv   = (float*)(wsw + 150160);   //  50048
    int*   bsum   = wsw + 200208;             //  64
    int*   boff   = wsw + 200272;             //  64
    int*   srcs   = wsw + 200336;             //  800000
    float* wsrc   = (float*)(wsw + 1000336);  //  800000
    float* T      = (float*)(wsw + 1800336);  //  NN*128

    // ----- CSR build (parallel scan) -----
    hipMemsetAsync(deg_i, 0, 50048 * sizeof(int), stream);
    deg_kernel<<<(NE + 255) / 256, 256, 0, stream>>>(dst, deg_i, NE);
    scan_part<<<NB, 256, 0, stream>>>(deg_i, bsum, NN);
    scan_tops<<<1, 64, 0, stream>>>(bsum, boff, rowptr + NN, NB);
    scan_fill<<<NB, 256, 0, stream>>>(deg_i, boff, rowptr, cursor, NN);
    dinv_kernel<<<(NN + 255) / 256, 256, 0, stream>>>(deg_i, dinv, NN);
    fill_kernel<<<(NE + 255) / 256, 256, 0, stream>>>(src, dst, dinv, cursor, srcs, wsrc, NE);

    const int gB = (NN + 63) / 64;   // gemm blocks
    const int aB = (NN + 3) / 4;     // gather blocks (wave per node)

    // ----- layer 1: x@W1 -> T [NN x 128] (two strided chunks), one wide gather -----
    gemm_kernel<128, 64, 128, 128><<<gB, 256, 0, stream>>>(x, W1, 0, 0, T, NN);
    gemm_kernel<128, 64, 128, 128><<<gB, 256, 0, stream>>>(x, W1, 64, 64, T, NN);
    gather_kernel<128, true><<<aB, 256, 0, stream>>>(rowptr, srcs, wsrc, dinv, T,
                                                     b1, out_h1, NN);
    // ----- layer 2: h1@W2 -> T [NN x 64], gather -----
    gemm_kernel<128, 64, 64, 64><<<gB, 256, 0, stream>>>(out_h1, W2, 0, 0, T, NN);
    gather_kernel<64, false><<<aB, 256, 0, stream>>>(rowptr, srcs, wsrc, dinv, T,
                                                     b2, out_h2, NN);
}

// Round 8
// 358.738 us; speedup vs baseline: 2.1159x; 1.0491x over previous
//
#include <hip/hip_runtime.h>
#include <hip/hip_bf16.h>

constexpr int NN = 50000;
constexpr int NE = 800000;
constexpr int SCAN_B = 1024;                      // elems per scan block
constexpr int NB = (NN + SCAN_B - 1) / SCAN_B;    // 49 scan blocks

__device__ __forceinline__ float bfu_to_f(unsigned int u16) {
    return __uint_as_float(u16 << 16);
}
// fp32 -> bf16 bits, round-to-nearest-even (finite inputs)
__device__ __forceinline__ unsigned short f_to_bfu(float f) {
    unsigned int u = __float_as_uint(f);
    return (unsigned short)((u + 0x7fffu + ((u >> 16) & 1u)) >> 16);
}

// ---------- degree (int) ----------
__global__ __launch_bounds__(256) void deg_kernel(const int* __restrict__ dst,
                                                  int* __restrict__ deg, int E) {
    int e = blockIdx.x * 256 + threadIdx.x;
    if (e < E) atomicAdd(&deg[dst[e]], 1);
}

__global__ __launch_bounds__(256) void dinv_kernel(const int* __restrict__ deg,
                                                   float* __restrict__ dinv, int M) {
    int i = blockIdx.x * 256 + threadIdx.x;
    if (i < M) dinv[i] = rsqrtf((float)deg[i] + 1.0f);  // +1 = self loop
}

// ---------- parallel scan, phase 1: per-block sums ----------
__global__ __launch_bounds__(256) void scan_part(const int* __restrict__ deg,
                                                 int* __restrict__ bsum, int n) {
    __shared__ int wred[4];
    const int tid = threadIdx.x, lane = tid & 63, wid = tid >> 6;
    int idx = blockIdx.x * SCAN_B + tid * 4;
    int s = 0;
#pragma unroll
    for (int j = 0; j < 4; j++) if (idx + j < n) s += deg[idx + j];
#pragma unroll
    for (int off = 32; off >= 1; off >>= 1) s += __shfl_xor(s, off);
    if (lane == 0) wred[wid] = s;
    __syncthreads();
    if (tid == 0) bsum[blockIdx.x] = wred[0] + wred[1] + wred[2] + wred[3];
}

// ---------- phase 2: one-wave exclusive scan of block sums ----------
__global__ __launch_bounds__(64) void scan_tops(const int* __restrict__ bsum,
                                                int* __restrict__ boff,
                                                int* __restrict__ total_out, int nb) {
    int lane = threadIdx.x;
    int v = (lane < nb) ? bsum[lane] : 0;
    int incl = v;
#pragma unroll
    for (int off = 1; off < 64; off <<= 1) {
        int t = __shfl_up(incl, off, 64);
        if (lane >= off) incl += t;
    }
    if (lane < nb) boff[lane] = incl - v;
    if (lane == 63) total_out[0] = incl;   // = rowptr[n]
}

// ---------- phase 3: per-block scan + global offset -> rowptr & cursor ----------
__global__ __launch_bounds__(256) void scan_fill(const int* __restrict__ deg,
                                                 const int* __restrict__ boff,
                                                 int* __restrict__ rowptr,
                                                 int* __restrict__ cursor, int n) {
    __shared__ int wsum[4];
    __shared__ int woff[4];
    const int tid = threadIdx.x, lane = tid & 63, wid = tid >> 6;
    int idx = blockIdx.x * SCAN_B + tid * 4;
    int v0 = (idx + 0 < n) ? deg[idx + 0] : 0;
    int v1 = (idx + 1 < n) ? deg[idx + 1] : 0;
    int v2 = (idx + 2 < n) ? deg[idx + 2] : 0;
    int v3 = (idx + 3 < n) ? deg[idx + 3] : 0;
    int local = v0 + v1 + v2 + v3;
    int incl = local;
#pragma unroll
    for (int off = 1; off < 64; off <<= 1) {
        int t = __shfl_up(incl, off, 64);
        if (lane >= off) incl += t;
    }
    if (lane == 63) wsum[wid] = incl;
    __syncthreads();
    if (tid == 0) {
        int acc = boff[blockIdx.x];
        for (int w = 0; w < 4; w++) { woff[w] = acc; acc += wsum[w]; }
    }
    __syncthreads();
    int p = woff[wid] + (incl - local);
    if (idx + 0 < n) { rowptr[idx + 0] = p; cursor[idx + 0] = p; } p += v0;
    if (idx + 1 < n) { rowptr[idx + 1] = p; cursor[idx + 1] = p; } p += v1;
    if (idx + 2 < n) { rowptr[idx + 2] = p; cursor[idx + 2] = p; } p += v2;
    if (idx + 3 < n) { rowptr[idx + 3] = p; cursor[idx + 3] = p; }
}

// ---------- CSR fill: bucket edges by dst, fold dinv[src] per edge ----------
__global__ __launch_bounds__(256) void fill_kernel(const int* __restrict__ src,
                                                   const int* __restrict__ dst,
                                                   const float* __restrict__ dinv,
                                                   int* __restrict__ cursor,
                                                   int* __restrict__ srcs,
                                                   float* __restrict__ wsrc, int E) {
    int e = blockIdx.x * 256 + threadIdx.x;
    if (e >= E) return;
    int s = src[e], t = dst[e];
    int pos = atomicAdd(&cursor[t], 1);
    srcs[pos] = s;
    wsrc[pos] = dinv[s];
}

// ---------- GEMM: H[:, oc0:oc0+N] = X[M x K] @ W[:, wc0:wc0+N]  (fp32 math) ----------
// 4x4 register blocking, b128 LDS reads, K-tiled W staging. Output: bf16 (ushort).
template <int K, int N, int WN, int OS>
__global__ __launch_bounds__(256) void gemm_kernel(const float* __restrict__ X,
                                                   const float* __restrict__ W,
                                                   int wc0, int oc0,
                                                   unsigned short* __restrict__ H, int M) {
    constexpr int ROWS = 64;
    constexpr int KT   = 64;          // K-tile for W staging
    constexpr int XS   = K + 4;       // padded X row stride (floats)
    constexpr int CP   = N / 4;       // col groups (float4 each)
    constexpr int NRG  = 256 / CP;
    constexpr int RPT  = ROWS / NRG;  // rows per thread (=4)

    __shared__ float Xs[ROWS * XS];
    __shared__ float Ws[KT * N];

    const int tid = threadIdx.x;
    const int rb  = blockIdx.x * ROWS;
    const int cp  = tid % CP;
    const int rg  = tid / CP;
    const int r0  = rg * RPT;

    // stage X rows [rb, rb+ROWS) into padded LDS, float4, zero-fill OOB
    {
        const float4* Xv  = reinterpret_cast<const float4*>(X + (size_t)rb * K);
        float4*       Xsv = reinterpret_cast<float4*>(Xs);
        constexpr int VPR = K / 4;  // float4 per row
        for (int i = tid; i < ROWS * VPR; i += 256) {
            int r = i / VPR, j = i - r * VPR;
            float4 v = make_float4(0.f, 0.f, 0.f, 0.f);
            if (rb + r < M) v = Xv[i];
            Xsv[r * (XS / 4) + j] = v;
        }
    }

    float4 acc[RPT];
#pragma unroll
    for (int i = 0; i < RPT; i++) acc[i] = make_float4(0.f, 0.f, 0.f, 0.f);

    for (int kt = 0; kt < K; kt += KT) {
        {
            const float4* Wv  = reinterpret_cast<const float4*>(W);
            float4*       Wsv = reinterpret_cast<float4*>(Ws);
            constexpr int VPW = N / 4;
            constexpr int VWR = WN / 4;
            const int cv0 = wc0 / 4;
            for (int i = tid; i < KT * VPW; i += 256) {
                int k = i / VPW, j = i - k * VPW;
                Wsv[i] = Wv[(kt + k) * VWR + cv0 + j];
            }
        }
        __syncthreads();

        const float4* Xs4 = reinterpret_cast<const float4*>(Xs);
        const float4* Ws4 = reinterpret_cast<const float4*>(Ws);
#pragma unroll 4
        for (int k4 = 0; k4 < KT; k4 += 4) {
            float4 xq[RPT];
#pragma unroll
            for (int i = 0; i < RPT; i++)
                xq[i] = Xs4[(r0 + i) * (XS / 4) + (kt + k4) / 4];
            float4 wq[4];
#pragma unroll
            for (int j = 0; j < 4; j++)
                wq[j] = Ws4[(k4 + j) * CP + cp];
#pragma unroll
            for (int j = 0; j < 4; j++) {
#pragma unroll
                for (int i = 0; i < RPT; i++) {
                    float xx = reinterpret_cast<const float*>(&xq[i])[j];
                    acc[i].x += xx * wq[j].x;
                    acc[i].y += xx * wq[j].y;
                    acc[i].z += xx * wq[j].z;
                    acc[i].w += xx * wq[j].w;
                }
            }
        }
        __syncthreads();
    }

#pragma unroll
    for (int i = 0; i < RPT; i++) {
        int row = rb + r0 + i;
        if (row < M) {
            ushort4 o;
            o.x = f_to_bfu(acc[i].x);
            o.y = f_to_bfu(acc[i].y);
            o.z = f_to_bfu(acc[i].z);
            o.w = f_to_bfu(acc[i].w);
            *reinterpret_cast<ushort4*>(H + (size_t)row * OS + oc0 + 4 * cp) = o;
        }
    }
}

// ---------- fused gather-aggregate + self-loop + bias (+relu): wave per node ----------
// h is bf16 [M x NW]; accumulators fp32; out fp32.
template <int NW, bool RELU>
__global__ __launch_bounds__(256) void gather_kernel(const int* __restrict__ rowptr,
                                                     const int* __restrict__ srcs,
                                                     const float* __restrict__ wsrc,
                                                     const float* __restrict__ dinv,
                                                     const unsigned short* __restrict__ h,
                                                     const float* __restrict__ b,
                                                     float* __restrict__ out, int M) {
    constexpr int VEC = NW / 64;   // bf16 per lane (1 or 2)
    const int lane = threadIdx.x & 63;
    const int wid  = threadIdx.x >> 6;
    const int t    = blockIdx.x * 4 + wid;
    if (t >= M) return;

    float acc0 = 0.f, acc1 = 0.f;
    const int beg = rowptr[t], end = rowptr[t + 1];
    for (int eb = beg; eb < end; eb += 64) {
        const int rem = end - eb;
        int   sv = 0;
        float wv = 0.f;
        if (lane < rem) { sv = srcs[eb + lane]; wv = wsrc[eb + lane]; }
        const int m = rem < 64 ? rem : 64;
        for (int j = 0; j < m; j++) {
            int   s = __shfl(sv, j);
            float w = __shfl(wv, j);
            if constexpr (VEC == 2) {
                unsigned int hv = *reinterpret_cast<const unsigned int*>(
                    h + (size_t)s * NW + lane * 2);
                acc0 += w * bfu_to_f(hv & 0xffffu);
                acc1 += w * bfu_to_f(hv >> 16);
            } else {
                acc0 += w * bfu_to_f(h[(size_t)s * NW + lane]);
            }
        }
    }
    const float di = dinv[t];
    float* op = out + (size_t)t * NW + lane * VEC;
    if constexpr (VEC == 2) {
        unsigned int hv = *reinterpret_cast<const unsigned int*>(
            h + (size_t)t * NW + lane * 2);
        float2 bv = *reinterpret_cast<const float2*>(b + lane * 2);
        float v0 = acc0 * di + bfu_to_f(hv & 0xffffu) * di * di + bv.x;
        float v1 = acc1 * di + bfu_to_f(hv >> 16) * di * di + bv.y;
        if (RELU) { v0 = fmaxf(v0, 0.f); v1 = fmaxf(v1, 0.f); }
        *reinterpret_cast<float2*>(op) = make_float2(v0, v1);
    } else {
        float hs = bfu_to_f(h[(size_t)t * NW + lane]);
        float v0 = acc0 * di + hs * di * di + b[lane];
        if (RELU) v0 = fmaxf(v0, 0.f);
        op[0] = v0;
    }
}

extern "C" void kernel_launch(void* const* d_in, const int* in_sizes, int n_in,
                              void* d_out, int out_size, void* d_ws, size_t ws_size,
                              hipStream_t stream) {
    const float* x  = (const float*)d_in[0];
    const int*   ei = (const int*)d_in[1];
    const float* W1 = (const float*)d_in[2];
    const float* b1 = (const float*)d_in[3];
    const float* W2 = (const float*)d_in[4];
    const float* b2 = (const float*)d_in[5];

    float* out_h2 = (float*)d_out;                 // [NN x 64]  (output 0)
    float* out_h1 = out_h2 + (size_t)NN * 64;      // [NN x 128] (output 1)

    const int* src = ei;        // edge_index[0]
    const int* dst = ei + NE;   // edge_index[1]

    // ws layout (4B words), ~20 MB total:
    int*   wsw    = (int*)d_ws;
    int*   deg_i  = wsw;                      //  50048
    int*   rowptr = wsw + 50048;              //  50064
    int*   cursor = wsw + 100112;             //  50048
    float* dinv   = (float*)(wsw + 150160);   //  50048
    int*   bsum   = wsw + 200208;             //  64
    int*   boff   = wsw + 200272;             //  64
    int*   srcs   = wsw + 200336;             //  800000
    float* wsrc   = (float*)(wsw + 1000336);  //  800000
    unsigned short* T = (unsigned short*)(wsw + 1800336);  // bf16 [NN x 128] = 12.8 MB

    // ----- CSR build (parallel scan) -----
    hipMemsetAsync(deg_i, 0, 50048 * sizeof(int), stream);
    deg_kernel<<<(NE + 255) / 256, 256, 0, stream>>>(dst, deg_i, NE);
    scan_part<<<NB, 256, 0, stream>>>(deg_i, bsum, NN);
    scan_tops<<<1, 64, 0, stream>>>(bsum, boff, rowptr + NN, NB);
    scan_fill<<<NB, 256, 0, stream>>>(deg_i, boff, rowptr, cursor, NN);
    dinv_kernel<<<(NN + 255) / 256, 256, 0, stream>>>(deg_i, dinv, NN);
    fill_kernel<<<(NE + 255) / 256, 256, 0, stream>>>(src, dst, dinv, cursor, srcs, wsrc, NE);

    const int gB = (NN + 63) / 64;   // gemm blocks
    const int aB = (NN + 3) / 4;     // gather blocks (wave per node)

    // ----- layer 1: x@W1 -> T bf16 [NN x 128], one wide gather -----
    gemm_kernel<128, 64, 128, 128><<<gB, 256, 0, stream>>>(x, W1, 0, 0, T, NN);
    gemm_kernel<128, 64, 128, 128><<<gB, 256, 0, stream>>>(x, W1, 64, 64, T, NN);
    gather_kernel<128, true><<<aB, 256, 0, stream>>>(rowptr, srcs, wsrc, dinv, T,
                                                     b1, out_h1, NN);
    // ----- layer 2: h1@W2 -> T bf16 [NN x 64], gather -----
    gemm_kernel<128, 64, 64, 64><<<gB, 256, 0, stream>>>(out_h1, W2, 0, 0, T, NN);
    gather_kernel<64, false><<<aB, 256, 0, stream>>>(rowptr, srcs, wsrc, dinv, T,
                                                     b2, out_h2, NN);
}

// Round 9
// 311.622 us; speedup vs baseline: 2.4359x; 1.1512x over previous
//
#include <hip/hip_runtime.h>
#include <hip/hip_bf16.h>

constexpr int NN = 50000;
constexpr int NE = 800000;
constexpr int SCAN_B = 1024;                      // elems per scan block
constexpr int NB = (NN + SCAN_B - 1) / SCAN_B;    // 49 scan blocks

__device__ __forceinline__ float bfu_to_f(unsigned int u16) {
    return __uint_as_float(u16 << 16);
}
// fp32 -> bf16 bits, round-to-nearest-even (finite inputs)
__device__ __forceinline__ unsigned short f_to_bfu(float f) {
    unsigned int u = __float_as_uint(f);
    return (unsigned short)((u + 0x7fffu + ((u >> 16) & 1u)) >> 16);
}

// ---------- degree (int) ----------
__global__ __launch_bounds__(256) void deg_kernel(const int* __restrict__ dst,
                                                  int* __restrict__ deg, int E) {
    int e = blockIdx.x * 256 + threadIdx.x;
    if (e < E) atomicAdd(&deg[dst[e]], 1);
}

__global__ __launch_bounds__(256) void dinv_kernel(const int* __restrict__ deg,
                                                   float* __restrict__ dinv, int M) {
    int i = blockIdx.x * 256 + threadIdx.x;
    if (i < M) dinv[i] = rsqrtf((float)deg[i] + 1.0f);  // +1 = self loop
}

// ---------- parallel scan, phase 1: per-block sums ----------
__global__ __launch_bounds__(256) void scan_part(const int* __restrict__ deg,
                                                 int* __restrict__ bsum, int n) {
    __shared__ int wred[4];
    const int tid = threadIdx.x, lane = tid & 63, wid = tid >> 6;
    int idx = blockIdx.x * SCAN_B + tid * 4;
    int s = 0;
#pragma unroll
    for (int j = 0; j < 4; j++) if (idx + j < n) s += deg[idx + j];
#pragma unroll
    for (int off = 32; off >= 1; off >>= 1) s += __shfl_xor(s, off);
    if (lane == 0) wred[wid] = s;
    __syncthreads();
    if (tid == 0) bsum[blockIdx.x] = wred[0] + wred[1] + wred[2] + wred[3];
}

// ---------- phase 2: one-wave exclusive scan of block sums ----------
__global__ __launch_bounds__(64) void scan_tops(const int* __restrict__ bsum,
                                                int* __restrict__ boff,
                                                int* __restrict__ total_out, int nb) {
    int lane = threadIdx.x;
    int v = (lane < nb) ? bsum[lane] : 0;
    int incl = v;
#pragma unroll
    for (int off = 1; off < 64; off <<= 1) {
        int t = __shfl_up(incl, off, 64);
        if (lane >= off) incl += t;
    }
    if (lane < nb) boff[lane] = incl - v;
    if (lane == 63) total_out[0] = incl;   // = rowptr[n]
}

// ---------- phase 3: per-block scan + global offset -> rowptr & cursor ----------
__global__ __launch_bounds__(256) void scan_fill(const int* __restrict__ deg,
                                                 const int* __restrict__ boff,
                                                 int* __restrict__ rowptr,
                                                 int* __restrict__ cursor, int n) {
    __shared__ int wsum[4];
    __shared__ int woff[4];
    const int tid = threadIdx.x, lane = tid & 63, wid = tid >> 6;
    int idx = blockIdx.x * SCAN_B + tid * 4;
    int v0 = (idx + 0 < n) ? deg[idx + 0] : 0;
    int v1 = (idx + 1 < n) ? deg[idx + 1] : 0;
    int v2 = (idx + 2 < n) ? deg[idx + 2] : 0;
    int v3 = (idx + 3 < n) ? deg[idx + 3] : 0;
    int local = v0 + v1 + v2 + v3;
    int incl = local;
#pragma unroll
    for (int off = 1; off < 64; off <<= 1) {
        int t = __shfl_up(incl, off, 64);
        if (lane >= off) incl += t;
    }
    if (lane == 63) wsum[wid] = incl;
    __syncthreads();
    if (tid == 0) {
        int acc = boff[blockIdx.x];
        for (int w = 0; w < 4; w++) { woff[w] = acc; acc += wsum[w]; }
    }
    __syncthreads();
    int p = woff[wid] + (incl - local);
    if (idx + 0 < n) { rowptr[idx + 0] = p; cursor[idx + 0] = p; } p += v0;
    if (idx + 1 < n) { rowptr[idx + 1] = p; cursor[idx + 1] = p; } p += v1;
    if (idx + 2 < n) { rowptr[idx + 2] = p; cursor[idx + 2] = p; } p += v2;
    if (idx + 3 < n) { rowptr[idx + 3] = p; cursor[idx + 3] = p; }
}

// ---------- CSR fill: bucket edges by dst, fold dinv[src] per edge ----------
__global__ __launch_bounds__(256) void fill_kernel(const int* __restrict__ src,
                                                   const int* __restrict__ dst,
                                                   const float* __restrict__ dinv,
                                                   int* __restrict__ cursor,
                                                   int* __restrict__ srcs,
                                                   float* __restrict__ wsrc, int E) {
    int e = blockIdx.x * 256 + threadIdx.x;
    if (e >= E) return;
    int s = src[e], t = dst[e];
    int pos = atomicAdd(&cursor[t], 1);
    srcs[pos] = s;
    wsrc[pos] = dinv[s];
}

// ---------- GEMM: H[:, oc0:oc0+N] = X[M x K] @ W[:, wc0:wc0+N]  (fp32 math) ----------
// 4x4 register blocking, b128 LDS reads, K-tiled W staging. Output: bf16 (ushort).
template <int K, int N, int WN, int OS>
__global__ __launch_bounds__(256) void gemm_kernel(const float* __restrict__ X,
                                                   const float* __restrict__ W,
                                                   int wc0, int oc0,
                                                   unsigned short* __restrict__ H, int M) {
    constexpr int ROWS = 64;
    constexpr int KT   = 64;          // K-tile for W staging
    constexpr int XS   = K + 4;       // padded X row stride (floats)
    constexpr int CP   = N / 4;       // col groups (float4 each)
    constexpr int NRG  = 256 / CP;
    constexpr int RPT  = ROWS / NRG;  // rows per thread (=4)

    __shared__ float Xs[ROWS * XS];
    __shared__ float Ws[KT * N];

    const int tid = threadIdx.x;
    const int rb  = blockIdx.x * ROWS;
    const int cp  = tid % CP;
    const int rg  = tid / CP;
    const int r0  = rg * RPT;

    // stage X rows [rb, rb+ROWS) into padded LDS, float4, zero-fill OOB
    {
        const float4* Xv  = reinterpret_cast<const float4*>(X + (size_t)rb * K);
        float4*       Xsv = reinterpret_cast<float4*>(Xs);
        constexpr int VPR = K / 4;  // float4 per row
        for (int i = tid; i < ROWS * VPR; i += 256) {
            int r = i / VPR, j = i - r * VPR;
            float4 v = make_float4(0.f, 0.f, 0.f, 0.f);
            if (rb + r < M) v = Xv[i];
            Xsv[r * (XS / 4) + j] = v;
        }
    }

    float4 acc[RPT];
#pragma unroll
    for (int i = 0; i < RPT; i++) acc[i] = make_float4(0.f, 0.f, 0.f, 0.f);

    for (int kt = 0; kt < K; kt += KT) {
        {
            const float4* Wv  = reinterpret_cast<const float4*>(W);
            float4*       Wsv = reinterpret_cast<float4*>(Ws);
            constexpr int VPW = N / 4;
            constexpr int VWR = WN / 4;
            const int cv0 = wc0 / 4;
            for (int i = tid; i < KT * VPW; i += 256) {
                int k = i / VPW, j = i - k * VPW;
                Wsv[i] = Wv[(kt + k) * VWR + cv0 + j];
            }
        }
        __syncthreads();

        const float4* Xs4 = reinterpret_cast<const float4*>(Xs);
        const float4* Ws4 = reinterpret_cast<const float4*>(Ws);
#pragma unroll 4
        for (int k4 = 0; k4 < KT; k4 += 4) {
            float4 xq[RPT];
#pragma unroll
            for (int i = 0; i < RPT; i++)
                xq[i] = Xs4[(r0 + i) * (XS / 4) + (kt + k4) / 4];
            float4 wq[4];
#pragma unroll
            for (int j = 0; j < 4; j++)
                wq[j] = Ws4[(k4 + j) * CP + cp];
#pragma unroll
            for (int j = 0; j < 4; j++) {
#pragma unroll
                for (int i = 0; i < RPT; i++) {
                    float xx = reinterpret_cast<const float*>(&xq[i])[j];
                    acc[i].x += xx * wq[j].x;
                    acc[i].y += xx * wq[j].y;
                    acc[i].z += xx * wq[j].z;
                    acc[i].w += xx * wq[j].w;
                }
            }
        }
        __syncthreads();
    }

#pragma unroll
    for (int i = 0; i < RPT; i++) {
        int row = rb + r0 + i;
        if (row < M) {
            ushort4 o;
            o.x = f_to_bfu(acc[i].x);
            o.y = f_to_bfu(acc[i].y);
            o.z = f_to_bfu(acc[i].z);
            o.w = f_to_bfu(acc[i].w);
            *reinterpret_cast<ushort4*>(H + (size_t)row * OS + oc0 + 4 * cp) = o;
        }
    }
}

// ---------- fused gather-aggregate + self-loop + bias (+relu): wave per node ----------
// h is bf16 [M x NW]; accumulators fp32; out fp32.
// Inner edge loop unrolled x4: 4 outstanding row loads per wave (MLP).
template <int NW, bool RELU>
__global__ __launch_bounds__(256) void gather_kernel(const int* __restrict__ rowptr,
                                                     const int* __restrict__ srcs,
                                                     const float* __restrict__ wsrc,
                                                     const float* __restrict__ dinv,
                                                     const unsigned short* __restrict__ h,
                                                     const float* __restrict__ b,
                                                     float* __restrict__ out, int M) {
    constexpr int VEC = NW / 64;   // bf16 per lane (1 or 2)
    const int lane = threadIdx.x & 63;
    const int wid  = threadIdx.x >> 6;
    const int t    = blockIdx.x * 4 + wid;
    if (t >= M) return;

    float acc0 = 0.f, acc1 = 0.f;
    const int beg = rowptr[t], end = rowptr[t + 1];
    for (int eb = beg; eb < end; eb += 64) {
        const int rem = end - eb;
        int   sv = 0;
        float wv = 0.f;
        if (lane < rem) { sv = srcs[eb + lane]; wv = wsrc[eb + lane]; }
        const int m = rem < 64 ? rem : 64;
        int j = 0;
        // 4-way unrolled body: issue 4 independent row loads, then consume
        for (; j + 4 <= m; j += 4) {
            int s0 = __shfl(sv, j + 0), s1 = __shfl(sv, j + 1);
            int s2 = __shfl(sv, j + 2), s3 = __shfl(sv, j + 3);
            float w0 = __shfl(wv, j + 0), w1 = __shfl(wv, j + 1);
            float w2 = __shfl(wv, j + 2), w3 = __shfl(wv, j + 3);
            if constexpr (VEC == 2) {
                unsigned int h0 = *reinterpret_cast<const unsigned int*>(h + (size_t)s0 * NW + lane * 2);
                unsigned int h1 = *reinterpret_cast<const unsigned int*>(h + (size_t)s1 * NW + lane * 2);
                unsigned int h2 = *reinterpret_cast<const unsigned int*>(h + (size_t)s2 * NW + lane * 2);
                unsigned int h3 = *reinterpret_cast<const unsigned int*>(h + (size_t)s3 * NW + lane * 2);
                acc0 += w0 * bfu_to_f(h0 & 0xffffu); acc1 += w0 * bfu_to_f(h0 >> 16);
                acc0 += w1 * bfu_to_f(h1 & 0xffffu); acc1 += w1 * bfu_to_f(h1 >> 16);
                acc0 += w2 * bfu_to_f(h2 & 0xffffu); acc1 += w2 * bfu_to_f(h2 >> 16);
                acc0 += w3 * bfu_to_f(h3 & 0xffffu); acc1 += w3 * bfu_to_f(h3 >> 16);
            } else {
                unsigned short h0 = h[(size_t)s0 * NW + lane];
                unsigned short h1 = h[(size_t)s1 * NW + lane];
                unsigned short h2 = h[(size_t)s2 * NW + lane];
                unsigned short h3 = h[(size_t)s3 * NW + lane];
                acc0 += w0 * bfu_to_f(h0) + w1 * bfu_to_f(h1)
                      + w2 * bfu_to_f(h2) + w3 * bfu_to_f(h3);
            }
        }
        for (; j < m; j++) {
            int   s = __shfl(sv, j);
            float w = __shfl(wv, j);
            if constexpr (VEC == 2) {
                unsigned int hv = *reinterpret_cast<const unsigned int*>(
                    h + (size_t)s * NW + lane * 2);
                acc0 += w * bfu_to_f(hv & 0xffffu);
                acc1 += w * bfu_to_f(hv >> 16);
            } else {
                acc0 += w * bfu_to_f(h[(size_t)s * NW + lane]);
            }
        }
    }
    const float di = dinv[t];
    float* op = out + (size_t)t * NW + lane * VEC;
    if constexpr (VEC == 2) {
        unsigned int hv = *reinterpret_cast<const unsigned int*>(
            h + (size_t)t * NW + lane * 2);
        float2 bv = *reinterpret_cast<const float2*>(b + lane * 2);
        float v0 = acc0 * di + bfu_to_f(hv & 0xffffu) * di * di + bv.x;
        float v1 = acc1 * di + bfu_to_f(hv >> 16) * di * di + bv.y;
        if (RELU) { v0 = fmaxf(v0, 0.f); v1 = fmaxf(v1, 0.f); }
        *reinterpret_cast<float2*>(op) = make_float2(v0, v1);
    } else {
        float hs = bfu_to_f(h[(size_t)t * NW + lane]);
        float v0 = acc0 * di + hs * di * di + b[lane];
        if (RELU) v0 = fmaxf(v0, 0.f);
        op[0] = v0;
    }
}

extern "C" void kernel_launch(void* const* d_in, const int* in_sizes, int n_in,
                              void* d_out, int out_size, void* d_ws, size_t ws_size,
                              hipStream_t stream) {
    const float* x  = (const float*)d_in[0];
    const int*   ei = (const int*)d_in[1];
    const float* W1 = (const float*)d_in[2];
    const float* b1 = (const float*)d_in[3];
    const float* W2 = (const float*)d_in[4];
    const float* b2 = (const float*)d_in[5];

    float* out_h2 = (float*)d_out;                 // [NN x 64]  (output 0)
    float* out_h1 = out_h2 + (size_t)NN * 64;      // [NN x 128] (output 1)

    const int* src = ei;        // edge_index[0]
    const int* dst = ei + NE;   // edge_index[1]

    // ws layout (4B words), ~20 MB total:
    int*   wsw    = (int*)d_ws;
    int*   deg_i  = wsw;                      //  50048
    int*   rowptr = wsw + 50048;              //  50064
    int*   cursor = wsw + 100112;             //  50048
    float* dinv   = (float*)(wsw + 150160);   //  50048
    int*   bsum   = wsw + 200208;             //  64
    int*   boff   = wsw + 200272;             //  64
    int*   srcs   = wsw + 200336;             //  800000
    float* wsrc   = (float*)(wsw + 1000336);  //  800000
    unsigned short* T = (unsigned short*)(wsw + 1800336);  // bf16 [NN x 128] = 12.8 MB

    // ----- CSR build (parallel scan) -----
    hipMemsetAsync(deg_i, 0, 50048 * sizeof(int), stream);
    deg_kernel<<<(NE + 255) / 256, 256, 0, stream>>>(dst, deg_i, NE);
    scan_part<<<NB, 256, 0, stream>>>(deg_i, bsum, NN);
    scan_tops<<<1, 64, 0, stream>>>(bsum, boff, rowptr + NN, NB);
    scan_fill<<<NB, 256, 0, stream>>>(deg_i, boff, rowptr, cursor, NN);
    dinv_kernel<<<(NN + 255) / 256, 256, 0, stream>>>(deg_i, dinv, NN);
    fill_kernel<<<(NE + 255) / 256, 256, 0, stream>>>(src, dst, dinv, cursor, srcs, wsrc, NE);

    const int gB = (NN + 63) / 64;   // gemm blocks
    const int aB = (NN + 3) / 4;     // gather blocks (wave per node)

    // ----- layer 1: x@W1 -> T bf16 [NN x 128], one wide gather -----
    gemm_kernel<128, 64, 128, 128><<<gB, 256, 0, stream>>>(x, W1, 0, 0, T, NN);
    gemm_kernel<128, 64, 128, 128><<<gB, 256, 0, stream>>>(x, W1, 64, 64, T, NN);
    gather_kernel<128, true><<<aB, 256, 0, stream>>>(rowptr, srcs, wsrc, dinv, T,
                                                     b1, out_h1, NN);
    // ----- layer 2: h1@W2 -> T bf16 [NN x 64], gather -----
    gemm_kernel<128, 64, 64, 64><<<gB, 256, 0, stream>>>(out_h1, W2, 0, 0, T, NN);
    gather_kernel<64, false><<<aB, 256, 0, stream>>>(rowptr, srcs, wsrc, dinv, T,
                                                     b2, out_h2, NN);
}

// Round 10
// 305.730 us; speedup vs baseline: 2.4828x; 1.0193x over previous
//
#include <hip/hip_runtime.h>
#include <hip/hip_bf16.h>

constexpr int NN = 50000;
constexpr int NE = 800000;
constexpr int SCAN_B = 1024;                      // elems per scan block
constexpr int NB = (NN + SCAN_B - 1) / SCAN_B;    // 49 scan blocks

__device__ __forceinline__ float bfu_to_f(unsigned int u16) {
    return __uint_as_float(u16 << 16);
}
// fp32 -> bf16 bits, round-to-nearest-even (finite inputs)
__device__ __forceinline__ unsigned short f_to_bfu(float f) {
    unsigned int u = __float_as_uint(f);
    return (unsigned short)((u + 0x7fffu + ((u >> 16) & 1u)) >> 16);
}

// ---------- degree (int) ----------
__global__ __launch_bounds__(256) void deg_kernel(const int* __restrict__ dst,
                                                  int* __restrict__ deg, int E) {
    int e = blockIdx.x * 256 + threadIdx.x;
    if (e < E) atomicAdd(&deg[dst[e]], 1);
}

__global__ __launch_bounds__(256) void dinv_kernel(const int* __restrict__ deg,
                                                   float* __restrict__ dinv, int M) {
    int i = blockIdx.x * 256 + threadIdx.x;
    if (i < M) dinv[i] = rsqrtf((float)deg[i] + 1.0f);  // +1 = self loop
}

// ---------- parallel scan, phase 1: per-block sums ----------
__global__ __launch_bounds__(256) void scan_part(const int* __restrict__ deg,
                                                 int* __restrict__ bsum, int n) {
    __shared__ int wred[4];
    const int tid = threadIdx.x, lane = tid & 63, wid = tid >> 6;
    int idx = blockIdx.x * SCAN_B + tid * 4;
    int s = 0;
#pragma unroll
    for (int j = 0; j < 4; j++) if (idx + j < n) s += deg[idx + j];
#pragma unroll
    for (int off = 32; off >= 1; off >>= 1) s += __shfl_xor(s, off);
    if (lane == 0) wred[wid] = s;
    __syncthreads();
    if (tid == 0) bsum[blockIdx.x] = wred[0] + wred[1] + wred[2] + wred[3];
}

// ---------- phase 2: one-wave exclusive scan of block sums ----------
__global__ __launch_bounds__(64) void scan_tops(const int* __restrict__ bsum,
                                                int* __restrict__ boff,
                                                int* __restrict__ total_out, int nb) {
    int lane = threadIdx.x;
    int v = (lane < nb) ? bsum[lane] : 0;
    int incl = v;
#pragma unroll
    for (int off = 1; off < 64; off <<= 1) {
        int t = __shfl_up(incl, off, 64);
        if (lane >= off) incl += t;
    }
    if (lane < nb) boff[lane] = incl - v;
    if (lane == 63) total_out[0] = incl;   // = rowptr[n]
}

// ---------- phase 3: per-block scan + global offset -> rowptr & cursor ----------
__global__ __launch_bounds__(256) void scan_fill(const int* __restrict__ deg,
                                                 const int* __restrict__ boff,
                                                 int* __restrict__ rowptr,
                                                 int* __restrict__ cursor, int n) {
    __shared__ int wsum[4];
    __shared__ int woff[4];
    const int tid = threadIdx.x, lane = tid & 63, wid = tid >> 6;
    int idx = blockIdx.x * SCAN_B + tid * 4;
    int v0 = (idx + 0 < n) ? deg[idx + 0] : 0;
    int v1 = (idx + 1 < n) ? deg[idx + 1] : 0;
    int v2 = (idx + 2 < n) ? deg[idx + 2] : 0;
    int v3 = (idx + 3 < n) ? deg[idx + 3] : 0;
    int local = v0 + v1 + v2 + v3;
    int incl = local;
#pragma unroll
    for (int off = 1; off < 64; off <<= 1) {
        int t = __shfl_up(incl, off, 64);
        if (lane >= off) incl += t;
    }
    if (lane == 63) wsum[wid] = incl;
    __syncthreads();
    if (tid == 0) {
        int acc = boff[blockIdx.x];
        for (int w = 0; w < 4; w++) { woff[w] = acc; acc += wsum[w]; }
    }
    __syncthreads();
    int p = woff[wid] + (incl - local);
    if (idx + 0 < n) { rowptr[idx + 0] = p; cursor[idx + 0] = p; } p += v0;
    if (idx + 1 < n) { rowptr[idx + 1] = p; cursor[idx + 1] = p; } p += v1;
    if (idx + 2 < n) { rowptr[idx + 2] = p; cursor[idx + 2] = p; } p += v2;
    if (idx + 3 < n) { rowptr[idx + 3] = p; cursor[idx + 3] = p; }
}

// ---------- CSR fill: bucket edges by dst; u16 src index only ----------
__global__ __launch_bounds__(256) void fill_kernel(const int* __restrict__ src,
                                                   const int* __restrict__ dst,
                                                   int* __restrict__ cursor,
                                                   unsigned short* __restrict__ srcs,
                                                   int E) {
    int e = blockIdx.x * 256 + threadIdx.x;
    if (e >= E) return;
    int s = src[e], t = dst[e];
    int pos = atomicAdd(&cursor[t], 1);
    srcs[pos] = (unsigned short)s;   // NN=50000 < 65536
}

// ---------- GEMM: H[:, oc0:oc0+N] = X[M x K] @ W[:, wc0:wc0+N]  (fp32 math) ----------
// 4x4 register blocking, b128 LDS reads, K-tiled W staging. Output: bf16 (ushort).
template <int K, int N, int WN, int OS>
__global__ __launch_bounds__(256) void gemm_kernel(const float* __restrict__ X,
                                                   const float* __restrict__ W,
                                                   int wc0, int oc0,
                                                   unsigned short* __restrict__ H, int M) {
    constexpr int ROWS = 64;
    constexpr int KT   = 64;          // K-tile for W staging
    constexpr int XS   = K + 4;       // padded X row stride (floats)
    constexpr int CP   = N / 4;       // col groups (float4 each)
    constexpr int NRG  = 256 / CP;
    constexpr int RPT  = ROWS / NRG;  // rows per thread (=4)

    __shared__ float Xs[ROWS * XS];
    __shared__ float Ws[KT * N];

    const int tid = threadIdx.x;
    const int rb  = blockIdx.x * ROWS;
    const int cp  = tid % CP;
    const int rg  = tid / CP;
    const int r0  = rg * RPT;

    // stage X rows [rb, rb+ROWS) into padded LDS, float4, zero-fill OOB
    {
        const float4* Xv  = reinterpret_cast<const float4*>(X + (size_t)rb * K);
        float4*       Xsv = reinterpret_cast<float4*>(Xs);
        constexpr int VPR = K / 4;  // float4 per row
        for (int i = tid; i < ROWS * VPR; i += 256) {
            int r = i / VPR, j = i - r * VPR;
            float4 v = make_float4(0.f, 0.f, 0.f, 0.f);
            if (rb + r < M) v = Xv[i];
            Xsv[r * (XS / 4) + j] = v;
        }
    }

    float4 acc[RPT];
#pragma unroll
    for (int i = 0; i < RPT; i++) acc[i] = make_float4(0.f, 0.f, 0.f, 0.f);

    for (int kt = 0; kt < K; kt += KT) {
        {
            const float4* Wv  = reinterpret_cast<const float4*>(W);
            float4*       Wsv = reinterpret_cast<float4*>(Ws);
            constexpr int VPW = N / 4;
            constexpr int VWR = WN / 4;
            const int cv0 = wc0 / 4;
            for (int i = tid; i < KT * VPW; i += 256) {
                int k = i / VPW, j = i - k * VPW;
                Wsv[i] = Wv[(kt + k) * VWR + cv0 + j];
            }
        }
        __syncthreads();

        const float4* Xs4 = reinterpret_cast<const float4*>(Xs);
        const float4* Ws4 = reinterpret_cast<const float4*>(Ws);
#pragma unroll 4
        for (int k4 = 0; k4 < KT; k4 += 4) {
            float4 xq[RPT];
#pragma unroll
            for (int i = 0; i < RPT; i++)
                xq[i] = Xs4[(r0 + i) * (XS / 4) + (kt + k4) / 4];
            float4 wq[4];
#pragma unroll
            for (int j = 0; j < 4; j++)
                wq[j] = Ws4[(k4 + j) * CP + cp];
#pragma unroll
            for (int j = 0; j < 4; j++) {
#pragma unroll
                for (int i = 0; i < RPT; i++) {
                    float xx = reinterpret_cast<const float*>(&xq[i])[j];
                    acc[i].x += xx * wq[j].x;
                    acc[i].y += xx * wq[j].y;
                    acc[i].z += xx * wq[j].z;
                    acc[i].w += xx * wq[j].w;
                }
            }
        }
        __syncthreads();
    }

#pragma unroll
    for (int i = 0; i < RPT; i++) {
        int row = rb + r0 + i;
        if (row < M) {
            ushort4 o;
            o.x = f_to_bfu(acc[i].x);
            o.y = f_to_bfu(acc[i].y);
            o.z = f_to_bfu(acc[i].z);
            o.w = f_to_bfu(acc[i].w);
            *reinterpret_cast<ushort4*>(H + (size_t)row * OS + oc0 + 4 * cp) = o;
        }
    }
}

// ---------- fused gather-aggregate + self-loop + bias (+relu): wave per node ----------
// h is bf16 [M x NW]; srcs is u16; per-edge weight = dinv[src] (L2-resident table).
// Inner edge loop unrolled x4: 4 outstanding row loads per wave (MLP).
template <int NW, bool RELU>
__global__ __launch_bounds__(256) void gather_kernel(const int* __restrict__ rowptr,
                                                     const unsigned short* __restrict__ srcs,
                                                     const float* __restrict__ dinv,
                                                     const unsigned short* __restrict__ h,
                                                     const float* __restrict__ b,
                                                     float* __restrict__ out, int M) {
    constexpr int VEC = NW / 64;   // bf16 per lane (1 or 2)
    const int lane = threadIdx.x & 63;
    const int wid  = threadIdx.x >> 6;
    const int t    = blockIdx.x * 4 + wid;
    if (t >= M) return;

    float acc0 = 0.f, acc1 = 0.f;
    const int beg = rowptr[t], end = rowptr[t + 1];
    for (int eb = beg; eb < end; eb += 64) {
        const int rem = end - eb;
        int   sv = 0;
        float wv = 0.f;
        if (lane < rem) { sv = (int)srcs[eb + lane]; wv = dinv[sv]; }
        const int m = rem < 64 ? rem : 64;
        int j = 0;
        // 4-way unrolled body: issue 4 independent row loads, then consume
        for (; j + 4 <= m; j += 4) {
            int s0 = __shfl(sv, j + 0), s1 = __shfl(sv, j + 1);
            int s2 = __shfl(sv, j + 2), s3 = __shfl(sv, j + 3);
            float w0 = __shfl(wv, j + 0), w1 = __shfl(wv, j + 1);
            float w2 = __shfl(wv, j + 2), w3 = __shfl(wv, j + 3);
            if constexpr (VEC == 2) {
                unsigned int h0 = *reinterpret_cast<const unsigned int*>(h + (size_t)s0 * NW + lane * 2);
                unsigned int h1 = *reinterpret_cast<const unsigned int*>(h + (size_t)s1 * NW + lane * 2);
                unsigned int h2 = *reinterpret_cast<const unsigned int*>(h + (size_t)s2 * NW + lane * 2);
                unsigned int h3 = *reinterpret_cast<const unsigned int*>(h + (size_t)s3 * NW + lane * 2);
                acc0 += w0 * bfu_to_f(h0 & 0xffffu); acc1 += w0 * bfu_to_f(h0 >> 16);
                acc0 += w1 * bfu_to_f(h1 & 0xffffu); acc1 += w1 * bfu_to_f(h1 >> 16);
                acc0 += w2 * bfu_to_f(h2 & 0xffffu); acc1 += w2 * bfu_to_f(h2 >> 16);
                acc0 += w3 * bfu_to_f(h3 & 0xffffu); acc1 += w3 * bfu_to_f(h3 >> 16);
            } else {
                unsigned short h0 = h[(size_t)s0 * NW + lane];
                unsigned short h1 = h[(size_t)s1 * NW + lane];
                unsigned short h2 = h[(size_t)s2 * NW + lane];
                unsigned short h3 = h[(size_t)s3 * NW + lane];
                acc0 += w0 * bfu_to_f(h0) + w1 * bfu_to_f(h1)
                      + w2 * bfu_to_f(h2) + w3 * bfu_to_f(h3);
            }
        }
        for (; j < m; j++) {
            int   s = __shfl(sv, j);
            float w = __shfl(wv, j);
            if constexpr (VEC == 2) {
                unsigned int hv = *reinterpret_cast<const unsigned int*>(
                    h + (size_t)s * NW + lane * 2);
                acc0 += w * bfu_to_f(hv & 0xffffu);
                acc1 += w * bfu_to_f(hv >> 16);
            } else {
                acc0 += w * bfu_to_f(h[(size_t)s * NW + lane]);
            }
        }
    }
    const float di = dinv[t];
    float* op = out + (size_t)t * NW + lane * VEC;
    if constexpr (VEC == 2) {
        unsigned int hv = *reinterpret_cast<const unsigned int*>(
            h + (size_t)t * NW + lane * 2);
        float2 bv = *reinterpret_cast<const float2*>(b + lane * 2);
        float v0 = acc0 * di + bfu_to_f(hv & 0xffffu) * di * di + bv.x;
        float v1 = acc1 * di + bfu_to_f(hv >> 16) * di * di + bv.y;
        if (RELU) { v0 = fmaxf(v0, 0.f); v1 = fmaxf(v1, 0.f); }
        *reinterpret_cast<float2*>(op) = make_float2(v0, v1);
    } else {
        float hs = bfu_to_f(h[(size_t)t * NW + lane]);
        float v0 = acc0 * di + hs * di * di + b[lane];
        if (RELU) v0 = fmaxf(v0, 0.f);
        op[0] = v0;
    }
}

extern "C" void kernel_launch(void* const* d_in, const int* in_sizes, int n_in,
                              void* d_out, int out_size, void* d_ws, size_t ws_size,
                              hipStream_t stream) {
    const float* x  = (const float*)d_in[0];
    const int*   ei = (const int*)d_in[1];
    const float* W1 = (const float*)d_in[2];
    const float* b1 = (const float*)d_in[3];
    const float* W2 = (const float*)d_in[4];
    const float* b2 = (const float*)d_in[5];

    float* out_h2 = (float*)d_out;                 // [NN x 64]  (output 0)
    float* out_h1 = out_h2 + (size_t)NN * 64;      // [NN x 128] (output 1)

    const int* src = ei;        // edge_index[0]
    const int* dst = ei + NE;   // edge_index[1]

    // ws layout (4B words), ~15.2 MB total:
    int*   wsw    = (int*)d_ws;
    int*   deg_i  = wsw;                      //  50048
    int*   rowptr = wsw + 50048;              //  50064
    int*   cursor = wsw + 100112;             //  50048
    float* dinv   = (float*)(wsw + 150160);   //  50048
    int*   bsum   = wsw + 200208;             //  64
    int*   boff   = wsw + 200272;             //  64
    unsigned short* srcs = (unsigned short*)(wsw + 200336);  // u16 [NE] = 400000 words
    unsigned short* T    = (unsigned short*)(wsw + 600336);  // bf16 [NN x 128] = 12.8 MB

    // ----- CSR build (parallel scan) -----
    hipMemsetAsync(deg_i, 0, 50048 * sizeof(int), stream);
    deg_kernel<<<(NE + 255) / 256, 256, 0, stream>>>(dst, deg_i, NE);
    scan_part<<<NB, 256, 0, stream>>>(deg_i, bsum, NN);
    scan_tops<<<1, 64, 0, stream>>>(bsum, boff, rowptr + NN, NB);
    scan_fill<<<NB, 256, 0, stream>>>(deg_i, boff, rowptr, cursor, NN);
    dinv_kernel<<<(NN + 255) / 256, 256, 0, stream>>>(deg_i, dinv, NN);
    fill_kernel<<<(NE + 255) / 256, 256, 0, stream>>>(src, dst, cursor, srcs, NE);

    const int gB = (NN + 63) / 64;   // gemm blocks
    const int aB = (NN + 3) / 4;     // gather blocks (wave per node)

    // ----- layer 1: x@W1 -> T bf16 [NN x 128], one wide gather -----
    gemm_kernel<128, 64, 128, 128><<<gB, 256, 0, stream>>>(x, W1, 0, 0, T, NN);
    gemm_kernel<128, 64, 128, 128><<<gB, 256, 0, stream>>>(x, W1, 64, 64, T, NN);
    gather_kernel<128, true><<<aB, 256, 0, stream>>>(rowptr, srcs, dinv, T,
                                                     b1, out_h1, NN);
    // ----- layer 2: h1@W2 -> T bf16 [NN x 64], gather -----
    gemm_kernel<128, 64, 64, 64><<<gB, 256, 0, stream>>>(out_h1, W2, 0, 0, T, NN);
    gather_kernel<64, false><<<aB, 256, 0, stream>>>(rowptr, srcs, dinv, T,
                                                     b2, out_h2, NN);
}

// Round 11
// 278.385 us; speedup vs baseline: 2.7267x; 1.0982x over previous
//
#include <hip/hip_runtime.h>
#include <hip/hip_bf16.h>

constexpr int NN = 50000;
constexpr int NE = 800000;
constexpr int SCAN_B = 1024;                      // elems per scan block
constexpr int NB = (NN + SCAN_B - 1) / SCAN_B;    // 49 scan blocks

__device__ __forceinline__ float bfu_to_f(unsigned int u16) {
    return __uint_as_float(u16 << 16);
}
// fp32 -> bf16 bits, round-to-nearest-even (finite inputs)
__device__ __forceinline__ unsigned short f_to_bfu(float f) {
    unsigned int u = __float_as_uint(f);
    return (unsigned short)((u + 0x7fffu + ((u >> 16) & 1u)) >> 16);
}

// ---------- rank: histogram + within-bucket rank in ONE atomic pass ----------
// cnt must be zeroed. After this kernel cnt[t] == deg(t).
__global__ __launch_bounds__(256) void rank_kernel(const int* __restrict__ dst,
                                                   int* __restrict__ cnt,
                                                   int* __restrict__ pos, int E) {
    int e = blockIdx.x * 256 + threadIdx.x;
    if (e >= E) return;
    pos[e] = atomicAdd(&cnt[dst[e]], 1);   // coalesced store of rank
}

__global__ __launch_bounds__(256) void dinv_kernel(const int* __restrict__ deg,
                                                   float* __restrict__ dinv, int M) {
    int i = blockIdx.x * 256 + threadIdx.x;
    if (i < M) dinv[i] = rsqrtf((float)deg[i] + 1.0f);  // +1 = self loop
}

// ---------- parallel scan, phase 1: per-block sums ----------
__global__ __launch_bounds__(256) void scan_part(const int* __restrict__ deg,
                                                 int* __restrict__ bsum, int n) {
    __shared__ int wred[4];
    const int tid = threadIdx.x, lane = tid & 63, wid = tid >> 6;
    int idx = blockIdx.x * SCAN_B + tid * 4;
    int s = 0;
#pragma unroll
    for (int j = 0; j < 4; j++) if (idx + j < n) s += deg[idx + j];
#pragma unroll
    for (int off = 32; off >= 1; off >>= 1) s += __shfl_xor(s, off);
    if (lane == 0) wred[wid] = s;
    __syncthreads();
    if (tid == 0) bsum[blockIdx.x] = wred[0] + wred[1] + wred[2] + wred[3];
}

// ---------- phase 2: one-wave exclusive scan of block sums ----------
__global__ __launch_bounds__(64) void scan_tops(const int* __restrict__ bsum,
                                                int* __restrict__ boff,
                                                int* __restrict__ total_out, int nb) {
    int lane = threadIdx.x;
    int v = (lane < nb) ? bsum[lane] : 0;
    int incl = v;
#pragma unroll
    for (int off = 1; off < 64; off <<= 1) {
        int t = __shfl_up(incl, off, 64);
        if (lane >= off) incl += t;
    }
    if (lane < nb) boff[lane] = incl - v;
    if (lane == 63) total_out[0] = incl;   // = rowptr[n]
}

// ---------- phase 3: per-block scan + global offset -> rowptr ----------
__global__ __launch_bounds__(256) void scan_fill(const int* __restrict__ deg,
                                                 const int* __restrict__ boff,
                                                 int* __restrict__ rowptr, int n) {
    __shared__ int wsum[4];
    __shared__ int woff[4];
    const int tid = threadIdx.x, lane = tid & 63, wid = tid >> 6;
    int idx = blockIdx.x * SCAN_B + tid * 4;
    int v0 = (idx + 0 < n) ? deg[idx + 0] : 0;
    int v1 = (idx + 1 < n) ? deg[idx + 1] : 0;
    int v2 = (idx + 2 < n) ? deg[idx + 2] : 0;
    int v3 = (idx + 3 < n) ? deg[idx + 3] : 0;
    int local = v0 + v1 + v2 + v3;
    int incl = local;
#pragma unroll
    for (int off = 1; off < 64; off <<= 1) {
        int t = __shfl_up(incl, off, 64);
        if (lane >= off) incl += t;
    }
    if (lane == 63) wsum[wid] = incl;
    __syncthreads();
    if (tid == 0) {
        int acc = boff[blockIdx.x];
        for (int w = 0; w < 4; w++) { woff[w] = acc; acc += wsum[w]; }
    }
    __syncthreads();
    int p = woff[wid] + (incl - local);
    if (idx + 0 < n) rowptr[idx + 0] = p; p += v0;
    if (idx + 1 < n) rowptr[idx + 1] = p; p += v1;
    if (idx + 2 < n) rowptr[idx + 2] = p; p += v2;
    if (idx + 3 < n) rowptr[idx + 3] = p;
}

// ---------- place: srcs[rowptr[dst]+pos] = src  (no atomics, fire-and-forget) ----------
__global__ __launch_bounds__(256) void place_kernel(const int* __restrict__ src,
                                                    const int* __restrict__ dst,
                                                    const int* __restrict__ rowptr,
                                                    const int* __restrict__ pos,
                                                    unsigned short* __restrict__ srcs,
                                                    int E) {
    int e = blockIdx.x * 256 + threadIdx.x;
    if (e >= E) return;
    srcs[rowptr[dst[e]] + pos[e]] = (unsigned short)src[e];   // NN < 65536
}

// ---------- GEMM: H[:, oc0:oc0+N] = X[M x K] @ W[:, wc0:wc0+N]  (fp32 math) ----------
// 4x4 register blocking, b128 LDS reads, K-tiled W staging. Output: bf16 (ushort).
template <int K, int N, int WN, int OS>
__global__ __launch_bounds__(256) void gemm_kernel(const float* __restrict__ X,
                                                   const float* __restrict__ W,
                                                   int wc0, int oc0,
                                                   unsigned short* __restrict__ H, int M) {
    constexpr int ROWS = 64;
    constexpr int KT   = 64;          // K-tile for W staging
    constexpr int XS   = K + 4;       // padded X row stride (floats)
    constexpr int CP   = N / 4;       // col groups (float4 each)
    constexpr int NRG  = 256 / CP;
    constexpr int RPT  = ROWS / NRG;  // rows per thread (=4)

    __shared__ float Xs[ROWS * XS];
    __shared__ float Ws[KT * N];

    const int tid = threadIdx.x;
    const int rb  = blockIdx.x * ROWS;
    const int cp  = tid % CP;
    const int rg  = tid / CP;
    const int r0  = rg * RPT;

    // stage X rows [rb, rb+ROWS) into padded LDS, float4, zero-fill OOB
    {
        const float4* Xv  = reinterpret_cast<const float4*>(X + (size_t)rb * K);
        float4*       Xsv = reinterpret_cast<float4*>(Xs);
        constexpr int VPR = K / 4;  // float4 per row
        for (int i = tid; i < ROWS * VPR; i += 256) {
            int r = i / VPR, j = i - r * VPR;
            float4 v = make_float4(0.f, 0.f, 0.f, 0.f);
            if (rb + r < M) v = Xv[i];
            Xsv[r * (XS / 4) + j] = v;
        }
    }

    float4 acc[RPT];
#pragma unroll
    for (int i = 0; i < RPT; i++) acc[i] = make_float4(0.f, 0.f, 0.f, 0.f);

    for (int kt = 0; kt < K; kt += KT) {
        {
            const float4* Wv  = reinterpret_cast<const float4*>(W);
            float4*       Wsv = reinterpret_cast<float4*>(Ws);
            constexpr int VPW = N / 4;
            constexpr int VWR = WN / 4;
            const int cv0 = wc0 / 4;
            for (int i = tid; i < KT * VPW; i += 256) {
                int k = i / VPW, j = i - k * VPW;
                Wsv[i] = Wv[(kt + k) * VWR + cv0 + j];
            }
        }
        __syncthreads();

        const float4* Xs4 = reinterpret_cast<const float4*>(Xs);
        const float4* Ws4 = reinterpret_cast<const float4*>(Ws);
#pragma unroll 4
        for (int k4 = 0; k4 < KT; k4 += 4) {
            float4 xq[RPT];
#pragma unroll
            for (int i = 0; i < RPT; i++)
                xq[i] = Xs4[(r0 + i) * (XS / 4) + (kt + k4) / 4];
            float4 wq[4];
#pragma unroll
            for (int j = 0; j < 4; j++)
                wq[j] = Ws4[(k4 + j) * CP + cp];
#pragma unroll
            for (int j = 0; j < 4; j++) {
#pragma unroll
                for (int i = 0; i < RPT; i++) {
                    float xx = reinterpret_cast<const float*>(&xq[i])[j];
                    acc[i].x += xx * wq[j].x;
                    acc[i].y += xx * wq[j].y;
                    acc[i].z += xx * wq[j].z;
                    acc[i].w += xx * wq[j].w;
                }
            }
        }
        __syncthreads();
    }

#pragma unroll
    for (int i = 0; i < RPT; i++) {
        int row = rb + r0 + i;
        if (row < M) {
            ushort4 o;
            o.x = f_to_bfu(acc[i].x);
            o.y = f_to_bfu(acc[i].y);
            o.z = f_to_bfu(acc[i].z);
            o.w = f_to_bfu(acc[i].w);
            *reinterpret_cast<ushort4*>(H + (size_t)row * OS + oc0 + 4 * cp) = o;
        }
    }
}

// ---------- fused gather-aggregate + self-loop + bias (+relu): wave per node ----------
// h is bf16 [M x NW]; srcs is u16; per-edge weight = dinv[src] (L2-resident table).
// Inner edge loop unrolled x4: 4 outstanding row loads per wave (MLP).
template <int NW, bool RELU>
__global__ __launch_bounds__(256) void gather_kernel(const int* __restrict__ rowptr,
                                                     const unsigned short* __restrict__ srcs,
                                                     const float* __restrict__ dinv,
                                                     const unsigned short* __restrict__ h,
                                                     const float* __restrict__ b,
                                                     float* __restrict__ out, int M) {
    constexpr int VEC = NW / 64;   // bf16 per lane (1 or 2)
    const int lane = threadIdx.x & 63;
    const int wid  = threadIdx.x >> 6;
    const int t    = blockIdx.x * 4 + wid;
    if (t >= M) return;

    float acc0 = 0.f, acc1 = 0.f;
    const int beg = rowptr[t], end = rowptr[t + 1];
    for (int eb = beg; eb < end; eb += 64) {
        const int rem = end - eb;
        int   sv = 0;
        float wv = 0.f;
        if (lane < rem) { sv = (int)srcs[eb + lane]; wv = dinv[sv]; }
        const int m = rem < 64 ? rem : 64;
        int j = 0;
        // 4-way unrolled body: issue 4 independent row loads, then consume
        for (; j + 4 <= m; j += 4) {
            int s0 = __shfl(sv, j + 0), s1 = __shfl(sv, j + 1);
            int s2 = __shfl(sv, j + 2), s3 = __shfl(sv, j + 3);
            float w0 = __shfl(wv, j + 0), w1 = __shfl(wv, j + 1);
            float w2 = __shfl(wv, j + 2), w3 = __shfl(wv, j + 3);
            if constexpr (VEC == 2) {
                unsigned int h0 = *reinterpret_cast<const unsigned int*>(h + (size_t)s0 * NW + lane * 2);
                unsigned int h1 = *reinterpret_cast<const unsigned int*>(h + (size_t)s1 * NW + lane * 2);
                unsigned int h2 = *reinterpret_cast<const unsigned int*>(h + (size_t)s2 * NW + lane * 2);
                unsigned int h3 = *reinterpret_cast<const unsigned int*>(h + (size_t)s3 * NW + lane * 2);
                acc0 += w0 * bfu_to_f(h0 & 0xffffu); acc1 += w0 * bfu_to_f(h0 >> 16);
                acc0 += w1 * bfu_to_f(h1 & 0xffffu); acc1 += w1 * bfu_to_f(h1 >> 16);
                acc0 += w2 * bfu_to_f(h2 & 0xffffu); acc1 += w2 * bfu_to_f(h2 >> 16);
                acc0 += w3 * bfu_to_f(h3 & 0xffffu); acc1 += w3 * bfu_to_f(h3 >> 16);
            } else {
                unsigned short h0 = h[(size_t)s0 * NW + lane];
                unsigned short h1 = h[(size_t)s1 * NW + lane];
                unsigned short h2 = h[(size_t)s2 * NW + lane];
                unsigned short h3 = h[(size_t)s3 * NW + lane];
                acc0 += w0 * bfu_to_f(h0) + w1 * bfu_to_f(h1)
                      + w2 * bfu_to_f(h2) + w3 * bfu_to_f(h3);
            }
        }
        for (; j < m; j++) {
            int   s = __shfl(sv, j);
            float w = __shfl(wv, j);
            if constexpr (VEC == 2) {
                unsigned int hv = *reinterpret_cast<const unsigned int*>(
                    h + (size_t)s * NW + lane * 2);
                acc0 += w * bfu_to_f(hv & 0xffffu);
                acc1 += w * bfu_to_f(hv >> 16);
            } else {
                acc0 += w * bfu_to_f(h[(size_t)s * NW + lane]);
            }
        }
    }
    const float di = dinv[t];
    float* op = out + (size_t)t * NW + lane * VEC;
    if constexpr (VEC == 2) {
        unsigned int hv = *reinterpret_cast<const unsigned int*>(
            h + (size_t)t * NW + lane * 2);
        float2 bv = *reinterpret_cast<const float2*>(b + lane * 2);
        float v0 = acc0 * di + bfu_to_f(hv & 0xffffu) * di * di + bv.x;
        float v1 = acc1 * di + bfu_to_f(hv >> 16) * di * di + bv.y;
        if (RELU) { v0 = fmaxf(v0, 0.f); v1 = fmaxf(v1, 0.f); }
        *reinterpret_cast<float2*>(op) = make_float2(v0, v1);
    } else {
        float hs = bfu_to_f(h[(size_t)t * NW + lane]);
        float v0 = acc0 * di + hs * di * di + b[lane];
        if (RELU) v0 = fmaxf(v0, 0.f);
        op[0] = v0;
    }
}

extern "C" void kernel_launch(void* const* d_in, const int* in_sizes, int n_in,
                              void* d_out, int out_size, void* d_ws, size_t ws_size,
                              hipStream_t stream) {
    const float* x  = (const float*)d_in[0];
    const int*   ei = (const int*)d_in[1];
    const float* W1 = (const float*)d_in[2];
    const float* b1 = (const float*)d_in[3];
    const float* W2 = (const float*)d_in[4];
    const float* b2 = (const float*)d_in[5];

    float* out_h2 = (float*)d_out;                 // [NN x 64]  (output 0)
    float* out_h1 = out_h2 + (size_t)NN * 64;      // [NN x 128] (output 1)

    const int* src = ei;        // edge_index[0]
    const int* dst = ei + NE;   // edge_index[1]

    // ws layout (4B words), ~18.2 MB total:
    int*   wsw    = (int*)d_ws;
    int*   cnt    = wsw;                      //  50048  (becomes deg after rank)
    int*   rowptr = wsw + 50048;              //  50064
    float* dinv   = (float*)(wsw + 100112);   //  50048
    int*   bsum   = wsw + 150160;             //  64
    int*   boff   = wsw + 150224;             //  64
    int*   pos    = wsw + 150288;             //  800000 (within-bucket rank)
    unsigned short* srcs = (unsigned short*)(wsw + 950288);   // u16 [NE]
    unsigned short* T    = (unsigned short*)(wsw + 1350288);  // bf16 [NN x 128]

    // ----- CSR build: ONE atomic pass (rank) + scan + atomic-free place -----
    hipMemsetAsync(cnt, 0, 50048 * sizeof(int), stream);
    rank_kernel<<<(NE + 255) / 256, 256, 0, stream>>>(dst, cnt, pos, NE);
    scan_part<<<NB, 256, 0, stream>>>(cnt, bsum, NN);
    scan_tops<<<1, 64, 0, stream>>>(bsum, boff, rowptr + NN, NB);
    scan_fill<<<NB, 256, 0, stream>>>(cnt, boff, rowptr, NN);
    dinv_kernel<<<(NN + 255) / 256, 256, 0, stream>>>(cnt, dinv, NN);
    place_kernel<<<(NE + 255) / 256, 256, 0, stream>>>(src, dst, rowptr, pos, srcs, NE);

    const int gB = (NN + 63) / 64;   // gemm blocks
    const int aB = (NN + 3) / 4;     // gather blocks (wave per node)

    // ----- layer 1: x@W1 -> T bf16 [NN x 128], one wide gather -----
    gemm_kernel<128, 64, 128, 128><<<gB, 256, 0, stream>>>(x, W1, 0, 0, T, NN);
    gemm_kernel<128, 64, 128, 128><<<gB, 256, 0, stream>>>(x, W1, 64, 64, T, NN);
    gather_kernel<128, true><<<aB, 256, 0, stream>>>(rowptr, srcs, dinv, T,
                                                     b1, out_h1, NN);
    // ----- layer 2: h1@W2 -> T bf16 [NN x 64], gather -----
    gemm_kernel<128, 64, 64, 64><<<gB, 256, 0, stream>>>(out_h1, W2, 0, 0, T, NN);
    gather_kernel<64, false><<<aB, 256, 0, stream>>>(rowptr, srcs, dinv, T,
                                                     b2, out_h2, NN);
}

// Round 12
// 252.231 us; speedup vs baseline: 3.0094x; 1.1037x over previous
//
#include <hip/hip_runtime.h>
#include <hip/hip_bf16.h>

constexpr int NN  = 50000;
constexpr int NN2 = 50048;
constexpr int NE  = 800000;
constexpr int SCAN_B = 1024;
constexpr int NB = (NN + SCAN_B - 1) / SCAN_B;    // 49 scan blocks
constexpr int GB = (NN + 63) / 64;                // 782 gemm blocks per chunk
constexpr int RANK_BASE = 2 * GB;                 // first rank block in fused kernel
constexpr int RANK_BLOCKS = (NE + 255) / 256;     // 3125

__device__ __forceinline__ float bfu_to_f(unsigned int u16) {
    return __uint_as_float(u16 << 16);
}
__device__ __forceinline__ unsigned short f_to_bfu(float f) {
    unsigned int u = __float_as_uint(f);
    return (unsigned short)((u + 0x7fffu + ((u >> 16) & 1u)) >> 16);
}

// ---------- fused: layer-1 GEMM (2 chunks) + replicated rank histogram ----------
// blocks [0, GB)          : gemm chunk wc0=0
// blocks [GB, 2GB)        : gemm chunk wc0=64
// blocks [2GB, 2GB+3125)  : rank — pos[e] = atomicAdd(cnt[blockIdx%8][dst[e]], 1)
__global__ __launch_bounds__(256) void fused_gemm1_rank(
        const float* __restrict__ X, const float* __restrict__ W,
        unsigned short* __restrict__ H,
        const int* __restrict__ dst, int* __restrict__ cnt, int* __restrict__ pos) {
    constexpr int K = 128, N = 64, KT = 64, XS = K + 4;
    constexpr int CP = N / 4, RPT = 4;

    __shared__ float Xs[64 * XS];
    __shared__ float Ws[KT * N];

    const int bid = blockIdx.x;
    if (bid >= RANK_BASE) {
        // ---- rank role ----
        int e = (bid - RANK_BASE) * 256 + threadIdx.x;
        if (e < NE) {
            int rep = bid & 7;   // ~XCD id (round-robin dispatch heuristic)
            pos[e] = atomicAdd(&cnt[rep * NN2 + dst[e]], 1);
        }
        return;
    }

    // ---- gemm role ----
    const int chunk = (bid < GB) ? 0 : 1;
    const int wc0 = chunk * 64;
    const int tid = threadIdx.x;
    const int rb  = (bid - chunk * GB) * 64;
    const int cp  = tid % CP;
    const int rg  = tid / CP;
    const int r0  = rg * RPT;

    {
        const float4* Xv  = reinterpret_cast<const float4*>(X + (size_t)rb * K);
        float4*       Xsv = reinterpret_cast<float4*>(Xs);
        constexpr int VPR = K / 4;
        for (int i = tid; i < 64 * VPR; i += 256) {
            int r = i / VPR, j = i - r * VPR;
            float4 v = make_float4(0.f, 0.f, 0.f, 0.f);
            if (rb + r < NN) v = Xv[i];
            Xsv[r * (XS / 4) + j] = v;
        }
    }

    float4 acc[RPT];
#pragma unroll
    for (int i = 0; i < RPT; i++) acc[i] = make_float4(0.f, 0.f, 0.f, 0.f);

    for (int kt = 0; kt < K; kt += KT) {
        {
            const float4* Wv  = reinterpret_cast<const float4*>(W);
            float4*       Wsv = reinterpret_cast<float4*>(Ws);
            constexpr int VPW = N / 4, VWR = 128 / 4;
            const int cv0 = wc0 / 4;
            for (int i = tid; i < KT * VPW; i += 256) {
                int k = i / VPW, j = i - k * VPW;
                Wsv[i] = Wv[(kt + k) * VWR + cv0 + j];
            }
        }
        __syncthreads();

        const float4* Xs4 = reinterpret_cast<const float4*>(Xs);
        const float4* Ws4 = reinterpret_cast<const float4*>(Ws);
#pragma unroll 4
        for (int k4 = 0; k4 < KT; k4 += 4) {
            float4 xq[RPT];
#pragma unroll
            for (int i = 0; i < RPT; i++)
                xq[i] = Xs4[(r0 + i) * (XS / 4) + (kt + k4) / 4];
            float4 wq[4];
#pragma unroll
            for (int j = 0; j < 4; j++) wq[j] = Ws4[(k4 + j) * CP + cp];
#pragma unroll
            for (int j = 0; j < 4; j++) {
#pragma unroll
                for (int i = 0; i < RPT; i++) {
                    float xx = reinterpret_cast<const float*>(&xq[i])[j];
                    acc[i].x += xx * wq[j].x;
                    acc[i].y += xx * wq[j].y;
                    acc[i].z += xx * wq[j].z;
                    acc[i].w += xx * wq[j].w;
                }
            }
        }
        __syncthreads();
    }

#pragma unroll
    for (int i = 0; i < RPT; i++) {
        int row = rb + r0 + i;
        if (row < NN) {
            ushort4 o;
            o.x = f_to_bfu(acc[i].x); o.y = f_to_bfu(acc[i].y);
            o.z = f_to_bfu(acc[i].z); o.w = f_to_bfu(acc[i].w);
            *reinterpret_cast<ushort4*>(H + (size_t)row * 128 + wc0 + 4 * cp) = o;
        }
    }
}

// ---------- reduce replicas: deg, dinv, per-replica offsets, scan partials ----------
__global__ __launch_bounds__(256) void reduce_kernel(const int* __restrict__ cnt,
                                                     int* __restrict__ deg,
                                                     int* __restrict__ roff,
                                                     float* __restrict__ dinv,
                                                     int* __restrict__ bsum, int n) {
    __shared__ int wred[4];
    const int tid = threadIdx.x, lane = tid & 63, wid = tid >> 6;
    int t0 = blockIdx.x * SCAN_B + tid * 4;
    int local = 0;
#pragma unroll
    for (int j = 0; j < 4; j++) {
        int t = t0 + j;
        if (t < n) {
            int acc = 0;
#pragma unroll
            for (int r = 0; r < 8; r++) {
                roff[r * NN2 + t] = acc;
                acc += cnt[r * NN2 + t];
            }
            deg[t] = acc;
            dinv[t] = rsqrtf((float)acc + 1.0f);
            local += acc;
        }
    }
#pragma unroll
    for (int off = 32; off >= 1; off >>= 1) local += __shfl_xor(local, off);
    if (lane == 0) wred[wid] = local;
    __syncthreads();
    if (tid == 0) bsum[blockIdx.x] = wred[0] + wred[1] + wred[2] + wred[3];
}

// ---------- one-wave exclusive scan of block sums ----------
__global__ __launch_bounds__(64) void scan_tops(const int* __restrict__ bsum,
                                                int* __restrict__ boff,
                                                int* __restrict__ total_out, int nb) {
    int lane = threadIdx.x;
    int v = (lane < nb) ? bsum[lane] : 0;
    int incl = v;
#pragma unroll
    for (int off = 1; off < 64; off <<= 1) {
        int t = __shfl_up(incl, off, 64);
        if (lane >= off) incl += t;
    }
    if (lane < nb) boff[lane] = incl - v;
    if (lane == 63) total_out[0] = incl;
}

// ---------- per-block scan + global offset -> rowptr ----------
__global__ __launch_bounds__(256) void scan_fill(const int* __restrict__ deg,
                                                 const int* __restrict__ boff,
                                                 int* __restrict__ rowptr, int n) {
    __shared__ int wsum[4];
    __shared__ int woff[4];
    const int tid = threadIdx.x, lane = tid & 63, wid = tid >> 6;
    int idx = blockIdx.x * SCAN_B + tid * 4;
    int v0 = (idx + 0 < n) ? deg[idx + 0] : 0;
    int v1 = (idx + 1 < n) ? deg[idx + 1] : 0;
    int v2 = (idx + 2 < n) ? deg[idx + 2] : 0;
    int v3 = (idx + 3 < n) ? deg[idx + 3] : 0;
    int local = v0 + v1 + v2 + v3;
    int incl = local;
#pragma unroll
    for (int off = 1; off < 64; off <<= 1) {
        int t = __shfl_up(incl, off, 64);
        if (lane >= off) incl += t;
    }
    if (lane == 63) wsum[wid] = incl;
    __syncthreads();
    if (tid == 0) {
        int acc = boff[blockIdx.x];
        for (int w = 0; w < 4; w++) { woff[w] = acc; acc += wsum[w]; }
    }
    __syncthreads();
    int p = woff[wid] + (incl - local);
    if (idx + 0 < n) rowptr[idx + 0] = p; p += v0;
    if (idx + 1 < n) rowptr[idx + 1] = p; p += v1;
    if (idx + 2 < n) rowptr[idx + 2] = p; p += v2;
    if (idx + 3 < n) rowptr[idx + 3] = p;
}

// ---------- place: srcs[rowptr[t] + roff[rep][t] + pos[e]] = src[e] ----------
__global__ __launch_bounds__(256) void place_kernel(const int* __restrict__ src,
                                                    const int* __restrict__ dst,
                                                    const int* __restrict__ rowptr,
                                                    const int* __restrict__ roff,
                                                    const int* __restrict__ pos,
                                                    unsigned short* __restrict__ srcs,
                                                    int E) {
    int e = blockIdx.x * 256 + threadIdx.x;
    if (e >= E) return;
    int t = dst[e];
    int rep = (RANK_BASE + (e >> 8)) & 7;   // must match fused rank block mapping
    srcs[rowptr[t] + roff[rep * NN2 + t] + pos[e]] = (unsigned short)src[e];
}

// ---------- GEMM (standalone, layer 2) ----------
template <int K, int N, int WN, int OS>
__global__ __launch_bounds__(256) void gemm_kernel(const float* __restrict__ X,
                                                   const float* __restrict__ W,
                                                   int wc0, int oc0,
                                                   unsigned short* __restrict__ H, int M) {
    constexpr int ROWS = 64, KT = 64, XS = K + 4;
    constexpr int CP = N / 4, NRG = 256 / CP, RPT = ROWS / NRG;

    __shared__ float Xs[ROWS * XS];
    __shared__ float Ws[KT * N];

    const int tid = threadIdx.x;
    const int rb  = blockIdx.x * ROWS;
    const int cp  = tid % CP;
    const int rg  = tid / CP;
    const int r0  = rg * RPT;

    {
        const float4* Xv  = reinterpret_cast<const float4*>(X + (size_t)rb * K);
        float4*       Xsv = reinterpret_cast<float4*>(Xs);
        constexpr int VPR = K / 4;
        for (int i = tid; i < ROWS * VPR; i += 256) {
            int r = i / VPR, j = i - r * VPR;
            float4 v = make_float4(0.f, 0.f, 0.f, 0.f);
            if (rb + r < M) v = Xv[i];
            Xsv[r * (XS / 4) + j] = v;
        }
    }

    float4 acc[RPT];
#pragma unroll
    for (int i = 0; i < RPT; i++) acc[i] = make_float4(0.f, 0.f, 0.f, 0.f);

    for (int kt = 0; kt < K; kt += KT) {
        {
            const float4* Wv  = reinterpret_cast<const float4*>(W);
            float4*       Wsv = reinterpret_cast<float4*>(Ws);
            constexpr int VPW = N / 4, VWR = WN / 4;
            const int cv0 = wc0 / 4;
            for (int i = tid; i < KT * VPW; i += 256) {
                int k = i / VPW, j = i - k * VPW;
                Wsv[i] = Wv[(kt + k) * VWR + cv0 + j];
            }
        }
        __syncthreads();

        const float4* Xs4 = reinterpret_cast<const float4*>(Xs);
        const float4* Ws4 = reinterpret_cast<const float4*>(Ws);
#pragma unroll 4
        for (int k4 = 0; k4 < KT; k4 += 4) {
            float4 xq[RPT];
#pragma unroll
            for (int i = 0; i < RPT; i++)
                xq[i] = Xs4[(r0 + i) * (XS / 4) + (kt + k4) / 4];
            float4 wq[4];
#pragma unroll
            for (int j = 0; j < 4; j++) wq[j] = Ws4[(k4 + j) * CP + cp];
#pragma unroll
            for (int j = 0; j < 4; j++) {
#pragma unroll
                for (int i = 0; i < RPT; i++) {
                    float xx = reinterpret_cast<const float*>(&xq[i])[j];
                    acc[i].x += xx * wq[j].x;
                    acc[i].y += xx * wq[j].y;
                    acc[i].z += xx * wq[j].z;
                    acc[i].w += xx * wq[j].w;
                }
            }
        }
        __syncthreads();
    }

#pragma unroll
    for (int i = 0; i < RPT; i++) {
        int row = rb + r0 + i;
        if (row < M) {
            ushort4 o;
            o.x = f_to_bfu(acc[i].x); o.y = f_to_bfu(acc[i].y);
            o.z = f_to_bfu(acc[i].z); o.w = f_to_bfu(acc[i].w);
            *reinterpret_cast<ushort4*>(H + (size_t)row * OS + oc0 + 4 * cp) = o;
        }
    }
}

// ---------- fused gather-aggregate + self-loop + bias (+relu): wave per node ----------
template <int NW, bool RELU>
__global__ __launch_bounds__(256) void gather_kernel(const int* __restrict__ rowptr,
                                                     const unsigned short* __restrict__ srcs,
                                                     const float* __restrict__ dinv,
                                                     const unsigned short* __restrict__ h,
                                                     const float* __restrict__ b,
                                                     float* __restrict__ out, int M) {
    constexpr int VEC = NW / 64;
    const int lane = threadIdx.x & 63;
    const int wid  = threadIdx.x >> 6;
    const int t    = blockIdx.x * 4 + wid;
    if (t >= M) return;

    float acc0 = 0.f, acc1 = 0.f;
    const int beg = rowptr[t], end = rowptr[t + 1];
    for (int eb = beg; eb < end; eb += 64) {
        const int rem = end - eb;
        int   sv = 0;
        float wv = 0.f;
        if (lane < rem) { sv = (int)srcs[eb + lane]; wv = dinv[sv]; }
        const int m = rem < 64 ? rem : 64;
        int j = 0;
        for (; j + 4 <= m; j += 4) {
            int s0 = __shfl(sv, j + 0), s1 = __shfl(sv, j + 1);
            int s2 = __shfl(sv, j + 2), s3 = __shfl(sv, j + 3);
            float w0 = __shfl(wv, j + 0), w1 = __shfl(wv, j + 1);
            float w2 = __shfl(wv, j + 2), w3 = __shfl(wv, j + 3);
            if constexpr (VEC == 2) {
                unsigned int h0 = *reinterpret_cast<const unsigned int*>(h + (size_t)s0 * NW + lane * 2);
                unsigned int h1 = *reinterpret_cast<const unsigned int*>(h + (size_t)s1 * NW + lane * 2);
                unsigned int h2 = *reinterpret_cast<const unsigned int*>(h + (size_t)s2 * NW + lane * 2);
                unsigned int h3 = *reinterpret_cast<const unsigned int*>(h + (size_t)s3 * NW + lane * 2);
                acc0 += w0 * bfu_to_f(h0 & 0xffffu); acc1 += w0 * bfu_to_f(h0 >> 16);
                acc0 += w1 * bfu_to_f(h1 & 0xffffu); acc1 += w1 * bfu_to_f(h1 >> 16);
                acc0 += w2 * bfu_to_f(h2 & 0xffffu); acc1 += w2 * bfu_to_f(h2 >> 16);
                acc0 += w3 * bfu_to_f(h3 & 0xffffu); acc1 += w3 * bfu_to_f(h3 >> 16);
            } else {
                unsigned short h0 = h[(size_t)s0 * NW + lane];
                unsigned short h1 = h[(size_t)s1 * NW + lane];
                unsigned short h2 = h[(size_t)s2 * NW + lane];
                unsigned short h3 = h[(size_t)s3 * NW + lane];
                acc0 += w0 * bfu_to_f(h0) + w1 * bfu_to_f(h1)
                      + w2 * bfu_to_f(h2) + w3 * bfu_to_f(h3);
            }
        }
        for (; j < m; j++) {
            int   s = __shfl(sv, j);
            float w = __shfl(wv, j);
            if constexpr (VEC == 2) {
                unsigned int hv = *reinterpret_cast<const unsigned int*>(
                    h + (size_t)s * NW + lane * 2);
                acc0 += w * bfu_to_f(hv & 0xffffu);
                acc1 += w * bfu_to_f(hv >> 16);
            } else {
                acc0 += w * bfu_to_f(h[(size_t)s * NW + lane]);
            }
        }
    }
    const float di = dinv[t];
    float* op = out + (size_t)t * NW + lane * VEC;
    if constexpr (VEC == 2) {
        unsigned int hv = *reinterpret_cast<const unsigned int*>(
            h + (size_t)t * NW + lane * 2);
        float2 bv = *reinterpret_cast<const float2*>(b + lane * 2);
        float v0 = acc0 * di + bfu_to_f(hv & 0xffffu) * di * di + bv.x;
        float v1 = acc1 * di + bfu_to_f(hv >> 16) * di * di + bv.y;
        if (RELU) { v0 = fmaxf(v0, 0.f); v1 = fmaxf(v1, 0.f); }
        *reinterpret_cast<float2*>(op) = make_float2(v0, v1);
    } else {
        float hs = bfu_to_f(h[(size_t)t * NW + lane]);
        float v0 = acc0 * di + hs * di * di + b[lane];
        if (RELU) v0 = fmaxf(v0, 0.f);
        op[0] = v0;
    }
}

extern "C" void kernel_launch(void* const* d_in, const int* in_sizes, int n_in,
                              void* d_out, int out_size, void* d_ws, size_t ws_size,
                              hipStream_t stream) {
    const float* x  = (const float*)d_in[0];
    const int*   ei = (const int*)d_in[1];
    const float* W1 = (const float*)d_in[2];
    const float* b1 = (const float*)d_in[3];
    const float* W2 = (const float*)d_in[4];
    const float* b2 = (const float*)d_in[5];

    float* out_h2 = (float*)d_out;                 // [NN x 64]
    float* out_h1 = out_h2 + (size_t)NN * 64;      // [NN x 128]

    const int* src = ei;
    const int* dst = ei + NE;

    // ws layout (4B words), ~21.5 MB of 256 MiB:
    int*   wsw    = (int*)d_ws;
    int*   cnt    = wsw;                        // 8*NN2 = 400384
    int*   deg    = wsw + 400384;               // 50048
    int*   rowptr = wsw + 450432;               // 50064
    float* dinv   = (float*)(wsw + 500496);     // 50048
    int*   bsum   = wsw + 550544;               // 64
    int*   boff   = wsw + 550608;               // 64
    int*   pos    = wsw + 550672;               // 800000
    int*   roff   = wsw + 1350672;              // 8*NN2 = 400384
    unsigned short* srcs = (unsigned short*)(wsw + 1751056);  // u16 [NE]
    unsigned short* T    = (unsigned short*)(wsw + 2151056);  // bf16 [NN x 128]

    // ----- fused: layer-1 GEMM (both chunks) + replicated rank histogram -----
    hipMemsetAsync(cnt, 0, 8 * NN2 * sizeof(int), stream);
    fused_gemm1_rank<<<RANK_BASE + RANK_BLOCKS, 256, 0, stream>>>(
        x, W1, T, dst, cnt, pos);

    // ----- CSR: reduce replicas -> scan -> place (atomic-free) -----
    reduce_kernel<<<NB, 256, 0, stream>>>(cnt, deg, roff, dinv, bsum, NN);
    scan_tops<<<1, 64, 0, stream>>>(bsum, boff, rowptr + NN, NB);
    scan_fill<<<NB, 256, 0, stream>>>(deg, boff, rowptr, NN);
    place_kernel<<<RANK_BLOCKS, 256, 0, stream>>>(src, dst, rowptr, roff, pos, srcs, NE);

    const int aB = (NN + 3) / 4;

    // ----- layer 1 gather -----
    gather_kernel<128, true><<<aB, 256, 0, stream>>>(rowptr, srcs, dinv, T,
                                                     b1, out_h1, NN);
    // ----- layer 2 -----
    gemm_kernel<128, 64, 64, 64><<<GB, 256, 0, stream>>>(out_h1, W2, 0, 0, T, NN);
    gather_kernel<64, false><<<aB, 256, 0, stream>>>(rowptr, srcs, dinv, T,
                                                     b2, out_h2, NN);
}